// Round 7
// baseline (505.109 us; speedup 1.0000x reference)
//
#include <hip/hip_runtime.h>

// ---------------------------------------------------------------------------
// MambaLatentBiMap: 2 branches (fwd / reversed) x 2 mamba layers + gates.
// Rows r = (j, b, l). Layer index for stage s, branch j: lidx = s + 2*j.
// MFMA GEMMs (gate, GEMM1, GEMM4) use EXACT 3-way bf16 splitting with all
// operands PRE-SPLIT into 3 u16 planes by their producers; 6 product terms
// (hh,hm,mh,mm,hl,lh) -> fp32-equivalent. Gate & GEMM4 are K-split (grid.z
// x2) for full-chip occupancy; partials summed by combine2 epilogue kernels.
// gemm_mfma carries __launch_bounds__(256,1): without it the compiler caps
// VGPRs at 88 (< ~118 live) and spills ~30 regs to scratch -> ~125 MB/dispatch
// of HBM write leak (round-6 counters: WRITE_SIZE 140 MB vs 16.8 MB output).
// Scan: chunked linear recurrence, CL=32.
// ---------------------------------------------------------------------------

#define LSEQ 1024
#define SCAN_CL 32
#define SCAN_NC 32
#define APAD 40   // LDS row stride in u16 (80 B = 5 x 16B, odd -> conflict-free)

typedef short bf16x8 __attribute__((ext_vector_type(8)));
typedef float f32x4 __attribute__((ext_vector_type(4)));

__device__ __forceinline__ float sigmoidf_(float x) { return 1.f / (1.f + __expf(-x)); }
__device__ __forceinline__ float siluf_(float x)    { return x / (1.f + __expf(-x)); }
__device__ __forceinline__ float softplusf_(float x){ return x > 20.f ? x : log1pf(__expf(x)); }

__device__ __forceinline__ unsigned short bf16rne_(float v) {
  unsigned u = __float_as_uint(v);
  return (unsigned short)((u + 0x7FFFu + ((u >> 16) & 1u)) >> 16);
}
__device__ __forceinline__ float bfto_(unsigned short h) {
  return __uint_as_float(((unsigned)h) << 16);
}
__device__ __forceinline__ void split3_(float v, unsigned short& h,
                                        unsigned short& m, unsigned short& l) {
  h = bf16rne_(v); float r = v - bfto_(h);
  m = bf16rne_(r); float r2 = r - bfto_(m);
  l = bf16rne_(r2);
}

// ---------------- prep: x (B,D,L) -> X planes rows (j,b,l) cols d ----------
__global__ __launch_bounds__(256) void prep_kernel(const float* __restrict__ x,
                                                   unsigned short* __restrict__ Xh,
                                                   unsigned short* __restrict__ Xm,
                                                   unsigned short* __restrict__ Xl) {
  long idx = (long)blockIdx.x * 256 + threadIdx.x;   // 2,097,152
  int d = (int)(idx & 255);
  long t = idx >> 8;
  int l = (int)(t & 1023);
  int t2 = (int)(t >> 10);
  int b = t2 & 3;
  int j = t2 >> 2;
  int lsrc = j ? (1023 - l) : l;
  float v = x[((long)(b * 256 + d)) * LSEQ + lsrc];
  split3_(v, Xh[idx], Xm[idx], Xl[idx]);
}

// ---------------- Aneg = -exp(Alog) ----------------------------------------
__global__ __launch_bounds__(256) void aneg_kernel(const float* __restrict__ Alog,
                                                   float* __restrict__ Aneg) {
  int idx = blockIdx.x * 256 + threadIdx.x;          // 32768
  Aneg[idx] = -__expf(Alog[idx]);
}

// ---------------- elementwise 3-way split (x for gate, Wg) -----------------
__global__ __launch_bounds__(256) void split3v_kernel(const float4* __restrict__ in,
                                                      ushort4* __restrict__ oh,
                                                      ushort4* __restrict__ om,
                                                      ushort4* __restrict__ ol, int n4) {
  int i = blockIdx.x * 256 + threadIdx.x;
  if (i >= n4) return;
  float4 v = in[i];
  ushort4 H, M, L;
  split3_(v.x, H.x, M.x, L.x); split3_(v.y, H.y, M.y, L.y);
  split3_(v.z, H.z, M.z, L.z); split3_(v.w, H.w, M.w, L.w);
  oh[i] = H; om[i] = M; ol[i] = L;
}

// ---------------- transpose + 3-way split: [Z][K][N] -> [Z][N][K] ----------
__global__ __launch_bounds__(256) void tconv3_kernel(const float* __restrict__ in,
                                                     unsigned short* __restrict__ oh,
                                                     unsigned short* __restrict__ om,
                                                     unsigned short* __restrict__ ol,
                                                     int K, int N) {
  __shared__ float T[32][33];
  int z = blockIdx.z;
  int n0 = blockIdx.x * 32, k0 = blockIdx.y * 32;
  int tx = threadIdx.x & 31, ty = threadIdx.x >> 5;   // 32 x 8
  const float* src = in + (long)z * K * N;
#pragma unroll
  for (int m = 0; m < 4; ++m)
    T[ty + 8 * m][tx] = src[(long)(k0 + ty + 8 * m) * N + n0 + tx];
  __syncthreads();
  long obase = (long)z * N * K;
#pragma unroll
  for (int m = 0; m < 4; ++m) {
    float v = T[tx][ty + 8 * m];
    long o = obase + (long)(n0 + ty + 8 * m) * K + k0 + tx;
    split3_(v, oh[o], om[o], ol[o]);
  }
}

// ---------------- MFMA 3-split bf16 GEMM (pre-split operands) --------------
// C[bz](128-tiles of MxN) = A[z](M x lda) * B[z](N x ldb)^T over K-half kh.
// KSPLIT=2: bz = z*2 + kh, loop KH = K/2. KSPLIT=1: bz = z, KH = K.
// Output: plain f32 (partial if KSPLIT=2).
template <int KSPLIT>
__global__ __launch_bounds__(256, 1)
void gemm_mfma(const unsigned short* __restrict__ Ah_g,
               const unsigned short* __restrict__ Am_g,
               const unsigned short* __restrict__ Al_g, long aZ, int lda,
               const unsigned short* __restrict__ Bh_g,
               const unsigned short* __restrict__ Bm_g,
               const unsigned short* __restrict__ Bl_g, long bZ, int ldb,
               float* __restrict__ C, long cZ, int N, int KH) {
  __shared__ unsigned short SA[3][128 * APAD];
  __shared__ unsigned short SB[3][128 * APAD];
  const int bz = blockIdx.z;
  const int z  = (KSPLIT == 2) ? (bz >> 1) : bz;
  const int kh = (KSPLIT == 2) ? (bz & 1) : 0;
  const int m0 = blockIdx.y * 128, n0 = blockIdx.x * 128;
  const int tid = threadIdx.x;
  const int sr = tid >> 1, sh16 = (tid & 1) << 4;
  const long aoff = (long)z * aZ + (long)(m0 + sr) * lda + (long)kh * KH + sh16;
  const long boff = (long)z * bZ + (long)(n0 + sr) * ldb + (long)kh * KH + sh16;
  const unsigned short* ga0 = Ah_g + aoff;
  const unsigned short* ga1 = Am_g + aoff;
  const unsigned short* ga2 = Al_g + aoff;
  const unsigned short* gb0 = Bh_g + boff;
  const unsigned short* gb1 = Bm_g + boff;
  const unsigned short* gb2 = Bl_g + boff;
  const int lw = sr * APAD + sh16;

  const int lane = tid & 63, w = tid >> 6;
  const int wr = w >> 1, wc = w & 1;
  const int fr = lane & 15, koff = (lane >> 4) * 8;
  const int abase = (wr * 64 + fr) * APAD + koff;
  const int bbase = (wc * 64 + fr) * APAD + koff;

  f32x4 acc[4][4];
#pragma unroll
  for (int i = 0; i < 4; ++i)
#pragma unroll
    for (int j = 0; j < 4; ++j)
#pragma unroll
      for (int q = 0; q < 4; ++q) acc[i][j][q] = 0.f;

  uint4 pf[12];
  pf[0]  = *(const uint4*)(ga0); pf[1]  = *(const uint4*)(ga0 + 8);
  pf[2]  = *(const uint4*)(ga1); pf[3]  = *(const uint4*)(ga1 + 8);
  pf[4]  = *(const uint4*)(ga2); pf[5]  = *(const uint4*)(ga2 + 8);
  pf[6]  = *(const uint4*)(gb0); pf[7]  = *(const uint4*)(gb0 + 8);
  pf[8]  = *(const uint4*)(gb1); pf[9]  = *(const uint4*)(gb1 + 8);
  pf[10] = *(const uint4*)(gb2); pf[11] = *(const uint4*)(gb2 + 8);

  for (int k0 = 0; k0 < KH; k0 += 32) {
    __syncthreads();
    *(uint4*)(&SA[0][lw]) = pf[0];  *(uint4*)(&SA[0][lw + 8]) = pf[1];
    *(uint4*)(&SA[1][lw]) = pf[2];  *(uint4*)(&SA[1][lw + 8]) = pf[3];
    *(uint4*)(&SA[2][lw]) = pf[4];  *(uint4*)(&SA[2][lw + 8]) = pf[5];
    *(uint4*)(&SB[0][lw]) = pf[6];  *(uint4*)(&SB[0][lw + 8]) = pf[7];
    *(uint4*)(&SB[1][lw]) = pf[8];  *(uint4*)(&SB[1][lw + 8]) = pf[9];
    *(uint4*)(&SB[2][lw]) = pf[10]; *(uint4*)(&SB[2][lw + 8]) = pf[11];
    __syncthreads();
    if (k0 + 32 < KH) {
      const int k1 = k0 + 32;
      pf[0]  = *(const uint4*)(ga0 + k1); pf[1]  = *(const uint4*)(ga0 + k1 + 8);
      pf[2]  = *(const uint4*)(ga1 + k1); pf[3]  = *(const uint4*)(ga1 + k1 + 8);
      pf[4]  = *(const uint4*)(ga2 + k1); pf[5]  = *(const uint4*)(ga2 + k1 + 8);
      pf[6]  = *(const uint4*)(gb0 + k1); pf[7]  = *(const uint4*)(gb0 + k1 + 8);
      pf[8]  = *(const uint4*)(gb1 + k1); pf[9]  = *(const uint4*)(gb1 + k1 + 8);
      pf[10] = *(const uint4*)(gb2 + k1); pf[11] = *(const uint4*)(gb2 + k1 + 8);
    }
    bf16x8 fb[3][4];
#pragma unroll
    for (int nf = 0; nf < 4; ++nf) {
      fb[0][nf] = *(const bf16x8*)(&SB[0][bbase + nf * (16 * APAD)]);
      fb[1][nf] = *(const bf16x8*)(&SB[1][bbase + nf * (16 * APAD)]);
      fb[2][nf] = *(const bf16x8*)(&SB[2][bbase + nf * (16 * APAD)]);
    }
#pragma unroll
    for (int mf = 0; mf < 4; ++mf) {
      bf16x8 fah = *(const bf16x8*)(&SA[0][abase + mf * (16 * APAD)]);
      bf16x8 fam = *(const bf16x8*)(&SA[1][abase + mf * (16 * APAD)]);
      bf16x8 fal = *(const bf16x8*)(&SA[2][abase + mf * (16 * APAD)]);
#pragma unroll
      for (int nf = 0; nf < 4; ++nf) {
        acc[mf][nf] = __builtin_amdgcn_mfma_f32_16x16x32_bf16(fah, fb[0][nf], acc[mf][nf], 0, 0, 0);
        acc[mf][nf] = __builtin_amdgcn_mfma_f32_16x16x32_bf16(fah, fb[1][nf], acc[mf][nf], 0, 0, 0);
        acc[mf][nf] = __builtin_amdgcn_mfma_f32_16x16x32_bf16(fam, fb[0][nf], acc[mf][nf], 0, 0, 0);
        acc[mf][nf] = __builtin_amdgcn_mfma_f32_16x16x32_bf16(fam, fb[1][nf], acc[mf][nf], 0, 0, 0);
        acc[mf][nf] = __builtin_amdgcn_mfma_f32_16x16x32_bf16(fah, fb[2][nf], acc[mf][nf], 0, 0, 0);
        acc[mf][nf] = __builtin_amdgcn_mfma_f32_16x16x32_bf16(fal, fb[0][nf], acc[mf][nf], 0, 0, 0);
      }
    }
  }

  float* Cz = C + (long)bz * cZ;
#pragma unroll
  for (int mf = 0; mf < 4; ++mf)
#pragma unroll
    for (int nf = 0; nf < 4; ++nf) {
      int col = n0 + wc * 64 + nf * 16 + fr;
      int row0 = m0 + wr * 64 + mf * 16 + (lane >> 4) * 4;
#pragma unroll
      for (int q = 0; q < 4; ++q)
        Cz[(long)(row0 + q) * N + col] = acc[mf][nf][q];
    }
}

// ---------------- combine2: sum two K-split partial planes + epilogue ------
// OP: 0 plain f32, 1 sigmoid(v + bias), 2 split3 -> planes
template <int OP>
__global__ __launch_bounds__(256)
void combine2_kernel(const float* __restrict__ P, long pz,
                     const float* __restrict__ bias, int nmask,
                     float* __restrict__ outF,
                     unsigned short* __restrict__ oh,
                     unsigned short* __restrict__ om,
                     unsigned short* __restrict__ ol, long oz) {
  int z = blockIdx.y;
  long i = (long)blockIdx.x * 256 + threadIdx.x;
  float v = P[(long)(2 * z) * pz + i] + P[(long)(2 * z + 1) * pz + i];
  long o = (long)z * oz + i;
  if (OP == 1) {
    outF[o] = sigmoidf_(v + bias[z * (nmask + 1) + (int)(i & nmask)]);
  } else if (OP == 0) {
    outF[o] = v;
  } else {
    split3_(v, oh[o], om[o], ol[o]);
  }
}

// ---------------- generic tiled fp32 GEMM (GEMM2, GEMM3) -------------------
template <int EPI>   // 0 none, 1 bias+softplus
__global__ __launch_bounds__(256)
void gemm_f32(const float* __restrict__ A, int lda, long aZ,
              const float* __restrict__ W, int ldw, long wZ,
              const float* __restrict__ Bias, long bZ,
              float* __restrict__ C, int ldc, long cZ,
              int M, int N, int K) {
  constexpr int BM = 128, BN = 64, BK = 16;
  __shared__ __align__(16) float As[BK][BM];
  __shared__ __align__(16) float Bs[BK][BN];
  const int z = blockIdx.z;
  A += (long)z * aZ;
  W += (long)z * wZ;
  C += (long)z * cZ;
  const float* bias = (EPI != 0) ? (Bias + (long)z * bZ) : nullptr;
  const int m0 = blockIdx.y * BM, n0 = blockIdx.x * BN;
  const int tid = threadIdx.x;
  const int tx = tid & 15, ty = tid >> 4;

  float acc[8][4];
#pragma unroll
  for (int i = 0; i < 8; ++i)
#pragma unroll
    for (int jn = 0; jn < 4; ++jn) acc[i][jn] = 0.f;

  for (int k0 = 0; k0 < K; k0 += BK) {
#pragma unroll
    for (int i = 0; i < 2; ++i) {
      int idx = tid + i * 256;
      int m = idx >> 2, k4 = (idx & 3) << 2;
      float4 v = *(const float4*)(A + (long)(m0 + m) * lda + k0 + k4);
      As[k4 + 0][m] = v.x; As[k4 + 1][m] = v.y;
      As[k4 + 2][m] = v.z; As[k4 + 3][m] = v.w;
    }
    {
      int k = tid >> 4, n4 = (tid & 15) << 2;
      float4 v = make_float4(0.f, 0.f, 0.f, 0.f);
      if (n0 + n4 < N) v = *(const float4*)(W + (long)(k0 + k) * ldw + n0 + n4);
      Bs[k][n4 + 0] = v.x; Bs[k][n4 + 1] = v.y;
      Bs[k][n4 + 2] = v.z; Bs[k][n4 + 3] = v.w;
    }
    __syncthreads();
#pragma unroll
    for (int kk = 0; kk < BK; ++kk) {
      float a[8], bb[4];
#pragma unroll
      for (int i = 0; i < 8; ++i) a[i] = As[kk][ty * 8 + i];
#pragma unroll
      for (int jn = 0; jn < 4; ++jn) bb[jn] = Bs[kk][tx * 4 + jn];
#pragma unroll
      for (int i = 0; i < 8; ++i)
#pragma unroll
        for (int jn = 0; jn < 4; ++jn) acc[i][jn] = fmaf(a[i], bb[jn], acc[i][jn]);
    }
    __syncthreads();
  }

  int n = n0 + tx * 4;
  if (n < N) {
#pragma unroll
    for (int i = 0; i < 8; ++i) {
      int m = m0 + ty * 8 + i;
      float4 v;
      float* vp = &v.x;
#pragma unroll
      for (int jn = 0; jn < 4; ++jn) {
        float val = acc[i][jn];
        if (EPI) val += bias[n + jn];
        if (EPI == 1) val = softplusf_(val);
        vp[jn] = val;
      }
      *(float4*)(C + (long)m * ldc + n) = v;
    }
  }
}

// ---------------- causal conv4 + silu --------------------------------------
__global__ __launch_bounds__(256) void conv_kernel(const float* __restrict__ UZ,
                                                   const float* __restrict__ Wconv,
                                                   const float* __restrict__ bconv,
                                                   float* __restrict__ uc, int stage) {
  long idx = (long)blockIdx.x * 256 + threadIdx.x;  // 8192*256
  int di = (int)(idx & 255);
  long r = idx >> 8;
  int l = (int)(r & 1023);
  int j = (int)(r >> 12);
  int lidx = stage + 2 * j;
  const float* wc = Wconv + (long)(lidx * 256 + di) * 4;
  float acc = bconv[lidx * 256 + di];
  const float* up = UZ + (r - 3) * 512 + di;
  if (l >= 3) {
    acc = fmaf(up[0], wc[0], acc);
    acc = fmaf(up[512], wc[1], acc);
    acc = fmaf(up[1024], wc[2], acc);
    acc = fmaf(up[1536], wc[3], acc);
  } else {
    for (int k = 3 - l; k < 4; ++k) acc = fmaf(up[(long)k * 512], wc[k], acc);
  }
  uc[idx] = acc * sigmoidf_(acc);
}

// ---------------- selective scan: chunked (CL=32) --------------------------
template <int PASS>
__global__ __launch_bounds__(256)
void scan_chunk_kernel(const float* __restrict__ dt,
                       const float* __restrict__ uc,
                       const float* __restrict__ UZ,
                       const float* __restrict__ proj,
                       const float* __restrict__ Aneg,
                       const float* __restrict__ Dskip,
                       float* __restrict__ HST,   // [8][NC][256][32]
                       float* __restrict__ DTS,   // [8][NC][256]
                       unsigned short* __restrict__ YGh,
                       unsigned short* __restrict__ YGm,
                       unsigned short* __restrict__ YGl, int stage) {
  __shared__ __align__(16) float BC[SCAN_CL][64];
  const int blk = blockIdx.x;
  const int chunk = blk & (SCAN_NC - 1);
  const int jb = blk >> 5;
  const int di = threadIdx.x;
  const int j = jb >> 2;
  const int lidx = stage + 2 * j;
  const long r0 = (long)jb * 1024 + (long)chunk * SCAN_CL;

  for (int e = threadIdx.x; e < SCAN_CL * 64; e += 256) {
    int l = e >> 6, col = e & 63;
    BC[l][col] = proj[(r0 + l) * 80 + 16 + col];
  }

  float A[32];
  {
    const float4* ap = (const float4*)(Aneg + ((long)(lidx * 256 + di)) * 32);
#pragma unroll
    for (int q = 0; q < 8; ++q) {
      float4 v = ap[q];
      A[4 * q] = v.x; A[4 * q + 1] = v.y; A[4 * q + 2] = v.z; A[4 * q + 3] = v.w;
    }
  }

  const long sbase = (((long)jb * SCAN_NC + chunk) * 256 + di) * 32;
  float h[32];
  if (PASS == 0) {
#pragma unroll
    for (int n = 0; n < 32; ++n) h[n] = 0.f;
  } else {
    const float4* hp = (const float4*)(HST + sbase);
#pragma unroll
    for (int q = 0; q < 8; ++q) {
      float4 v = hp[q];
      h[4 * q] = v.x; h[4 * q + 1] = v.y; h[4 * q + 2] = v.z; h[4 * q + 3] = v.w;
    }
  }

  float Dsk = 0.f, dtsum = 0.f;
  if (PASS == 1) Dsk = Dskip[lidx * 256 + di];

  __syncthreads();

  for (int l = 0; l < SCAN_CL; ++l) {
    const long r = r0 + l;
    float dtv = dt[r * 256 + di];
    float uv  = uc[r * 256 + di];
    float du  = dtv * uv;
    if (PASS == 0) dtsum += dtv;
    float yacc[4] = {0.f, 0.f, 0.f, 0.f};
    const float4* bc4 = (const float4*)&BC[l][0];
#pragma unroll
    for (int q = 0; q < 8; ++q) {
      float4 bv = bc4[q];
      float4 cv = bc4[8 + q];
      const float* bp = &bv.x;
      const float* cp = &cv.x;
#pragma unroll
      for (int k = 0; k < 4; ++k) {
        int n = 4 * q + k;
        float a = __expf(dtv * A[n]);
        h[n] = fmaf(a, h[n], du * bp[k]);
        yacc[n & 3] = fmaf(h[n], cp[k], yacc[n & 3]);
      }
    }
    if (PASS == 1) {
      float y = (yacc[0] + yacc[1]) + (yacc[2] + yacc[3]);
      float zv = UZ[r * 512 + 256 + di];
      float val = (y + uv * Dsk) * siluf_(zv);
      split3_(val, YGh[r * 256 + di], YGm[r * 256 + di], YGl[r * 256 + di]);
    }
  }

  if (PASS == 0) {
    float4* hp = (float4*)(HST + sbase);
#pragma unroll
    for (int q = 0; q < 8; ++q)
      hp[q] = make_float4(h[4 * q], h[4 * q + 1], h[4 * q + 2], h[4 * q + 3]);
    DTS[((long)jb * SCAN_NC + chunk) * 256 + di] = dtsum;
  }
}

// ---------------- scan pass 2: sequential chunk combine --------------------
__global__ __launch_bounds__(256)
void scan_combine_kernel(float* __restrict__ HST, const float* __restrict__ DTS,
                         const float* __restrict__ Aneg, int stage) {
  int t = blockIdx.x * 256 + threadIdx.x;   // 65536
  int n = t & 31;
  int di = (t >> 5) & 255;
  int jb = t >> 13;
  int lidx = stage + 2 * (jb >> 2);
  float A = Aneg[((long)(lidx * 256 + di)) * 32 + n];
  float hs = 0.f;
  for (int c = 0; c < SCAN_NC; ++c) {
    long base = ((long)jb * SCAN_NC + c) * 256 + di;
    long idx = base * 32 + n;
    float s = HST[idx];
    HST[idx] = hs;
    float P = __expf(A * DTS[base]);
    hs = fmaf(P, hs, s);
  }
}

// ---------------- final combine --------------------------------------------
__global__ __launch_bounds__(256) void combine_kernel(const float* __restrict__ H,
                                                      const float* __restrict__ gate,
                                                      const float* __restrict__ alpha,
                                                      const float* __restrict__ gamma,
                                                      const float* __restrict__ beta,
                                                      float* __restrict__ out) {
  long idx = (long)blockIdx.x * 256 + threadIdx.x;  // 1,048,576 (b,d,l)
  int l = (int)(idx & 1023);
  long t = idx >> 10;
  int d = (int)(t & 255);
  int b = (int)(t >> 8);
  int lr = 1023 - l;
  float h0 = H[(((long)b * 1024 + l) * 256) + d];
  float h1 = H[(((long)(4 + b) * 1024 + lr) * 256) + d];
  float g0 = gate[((long)(b * 256 + d)) * 1024 + l];
  float g1 = gate[(long)1024 * 1024 + ((long)(b * 256 + d)) * 1024 + lr];
  float m0 = (gamma[l] * tanhf(alpha[0] * h0) + beta[l]) * g0;
  float m1 = (gamma[1024 + lr] * tanhf(alpha[1] * h1) + beta[1024 + lr]) * g1;
  out[idx] = m0 + m1;
}

// ---------------------------------------------------------------------------
extern "C" void kernel_launch(void* const* d_in, const int* in_sizes, int n_in,
                              void* d_out, int out_size, void* d_ws, size_t ws_size,
                              hipStream_t stream) {
  const float* x     = (const float*)d_in[0];
  const float* Win   = (const float*)d_in[1];
  const float* Wconv = (const float*)d_in[2];
  const float* bconv = (const float*)d_in[3];
  const float* Wxp   = (const float*)d_in[4];
  const float* Wdt   = (const float*)d_in[5];
  const float* bdt   = (const float*)d_in[6];
  const float* Alog  = (const float*)d_in[7];
  const float* Dskip = (const float*)d_in[8];
  const float* Wout  = (const float*)d_in[9];
  const float* Wg    = (const float*)d_in[10];
  const float* bg    = (const float*)d_in[11];
  const float* alpha = (const float*)d_in[12];
  const float* gamma = (const float*)d_in[13];
  const float* beta  = (const float*)d_in[14];
  float* out = (float*)d_out;

  // ---- workspace layout (floats); total 20,873,216 f = 83.5 MB ----
  // UZ: stage activations (XF/H aliases). PG partials alias UC..DT.
  // XG planes alias GATE region (dead pre-gate). Wg planes alias YG planes
  // (dead until stage-0 scan pass1, gate GEMM runs before the loop).
  float* ws   = (float*)d_ws;
  float* UZ   = ws;                    // 4,194,304 f
  float* UC   = UZ + 4194304;          // 2,097,152 f
  float* PROJ = UC + 2097152;          // 655,360 f
  float* DT   = PROJ + 655360;         // 2,097,152 f
  float* GATE = DT + 2097152;          // 2,097,152 f
  float* ANEG = GATE + 2097152;        // 32,768 f
  float* HST  = ANEG + 32768;          // 2,097,152 f
  float* DTS  = HST + 2097152;         // 131,072 f
  unsigned short* Xpl  = (unsigned short*)(DTS + 131072);   // 3 x 2,097,152 u16
  unsigned short* YGpl = Xpl + 3 * 2097152;                 // 3 x 2,097,152 u16
  unsigned short* WinT = YGpl + 3 * 2097152;                // 3 x 524,288 u16
  unsigned short* WoutT = WinT + 3 * 524288;                // 3 x 262,144 u16
  // aliases
  float* PG  = UC;                          // 4 x 1,048,576 f partials
  float* XF  = UZ;                          // final H (stage-1 GEMM4 out)
  unsigned short* XGh = (unsigned short*)GATE;   // 3 x 1,048,576 u16
  unsigned short* XGm = XGh + 1048576;
  unsigned short* XGl = XGm + 1048576;
  unsigned short* Wgh = YGpl;                    // 3 x 2,097,152 u16
  unsigned short* Wgm = Wgh + 2097152;
  unsigned short* Wgl = Wgm + 2097152;
  unsigned short* Xh = Xpl, *Xm = Xpl + 2097152, *Xl = Xpl + 2 * 2097152;
  unsigned short* YGh = YGpl, *YGm = YGpl + 2097152, *YGl = YGpl + 2 * 2097152;
  unsigned short* WinTh = WinT, *WinTm = WinT + 524288, *WinTl = WinT + 2 * 524288;
  unsigned short* WoutTh = WoutT, *WoutTm = WoutT + 262144, *WoutTl = WoutT + 2 * 262144;

  // ---- prep / weight splitting ----
  prep_kernel<<<dim3(8192), dim3(256), 0, stream>>>(x, Xh, Xm, Xl);
  aneg_kernel<<<dim3(128), dim3(256), 0, stream>>>(Alog, ANEG);
  split3v_kernel<<<dim3(1024), dim3(256), 0, stream>>>(
      (const float4*)x, (ushort4*)XGh, (ushort4*)XGm, (ushort4*)XGl, 262144);
  split3v_kernel<<<dim3(2048), dim3(256), 0, stream>>>(
      (const float4*)Wg, (ushort4*)Wgh, (ushort4*)Wgm, (ushort4*)Wgl, 524288);
  tconv3_kernel<<<dim3(16, 8, 4), dim3(256), 0, stream>>>(Win, WinTh, WinTm, WinTl, 256, 512);
  tconv3_kernel<<<dim3(8, 8, 4), dim3(256), 0, stream>>>(Wout, WoutTh, WoutTm, WoutTl, 256, 256);

  // ---- gate: PG[z*2+kh] = x @ Wg[z]^T (K-half kh); GATE = sigmoid(sum+bg) ----
  gemm_mfma<2><<<dim3(8, 8, 4), dim3(256), 0, stream>>>(
      XGh, XGm, XGl, 0L, 1024,
      Wgh, Wgm, Wgl, (long)1024 * 1024, 1024,
      PG, (long)1024 * 1024, 1024, 512);
  combine2_kernel<1><<<dim3(4096, 2), dim3(256), 0, stream>>>(
      PG, (long)1024 * 1024, bg, 1023, GATE, nullptr, nullptr, nullptr,
      (long)1024 * 1024);

  for (int s = 0; s < 2; ++s) {
    // GEMM1: UZ = X @ Win[lidx]  (N=512, K=256, full chip: 256 blocks)
    gemm_mfma<1><<<dim3(4, 32, 2), dim3(256), 0, stream>>>(
        Xh, Xm, Xl, (long)4096 * 256, 256,
        WinTh + (long)s * 131072, WinTm + (long)s * 131072, WinTl + (long)s * 131072,
        (long)262144, 256,
        UZ, (long)4096 * 512, 512, 256);

    conv_kernel<<<dim3(8192), dim3(256), 0, stream>>>(UZ, Wconv, bconv, UC, s);

    // GEMM2: PROJ = UC @ Wxp[lidx] (N=80, fp32)
    gemm_f32<0><<<dim3(2, 32, 2), dim3(256), 0, stream>>>(
        UC, 256, (long)4096 * 256, Wxp + (long)s * 256 * 80, 80, (long)2 * 256 * 80,
        nullptr, 0, PROJ, 80, (long)4096 * 80, 4096, 80, 256);

    // GEMM3: DT = softplus(PROJ[:, :16] @ Wdt[lidx] + bdt[lidx])
    gemm_f32<1><<<dim3(4, 32, 2), dim3(256), 0, stream>>>(
        PROJ, 80, (long)4096 * 80, Wdt + (long)s * 16 * 256, 256, (long)2 * 16 * 256,
        bdt + s * 256, 512, DT, 256, (long)4096 * 256, 4096, 256, 16);

    // chunked selective scan (pass1 writes YG planes)
    scan_chunk_kernel<0><<<dim3(8 * SCAN_NC), dim3(256), 0, stream>>>(
        DT, UC, UZ, PROJ, ANEG, Dskip, HST, DTS, YGh, YGm, YGl, s);
    scan_combine_kernel<<<dim3(256), dim3(256), 0, stream>>>(HST, DTS, ANEG, s);
    scan_chunk_kernel<1><<<dim3(8 * SCAN_NC), dim3(256), 0, stream>>>(
        DT, UC, UZ, PROJ, ANEG, Dskip, HST, DTS, YGh, YGm, YGl, s);

    // GEMM4 (K-split): PG[z*2+kh] = YG @ Wout[lidx] (K-half), then combine
    gemm_mfma<2><<<dim3(2, 32, 4), dim3(256), 0, stream>>>(
        YGh, YGm, YGl, (long)4096 * 256, 256,
        WoutTh + (long)s * 65536, WoutTm + (long)s * 65536, WoutTl + (long)s * 65536,
        (long)131072, 256,
        PG, (long)4096 * 256, 256, 128);
    if (s == 0) {
      combine2_kernel<2><<<dim3(4096, 2), dim3(256), 0, stream>>>(
          PG, (long)4096 * 256, nullptr, 0, nullptr, Xh, Xm, Xl, (long)4096 * 256);
    } else {
      combine2_kernel<0><<<dim3(4096, 2), dim3(256), 0, stream>>>(
          PG, (long)4096 * 256, nullptr, 0, XF, nullptr, nullptr, nullptr,
          (long)4096 * 256);
    }
  }

  combine_kernel<<<dim3(4096), dim3(256), 0, stream>>>(XF, GATE, alpha, gamma, beta, out);
}

// Round 8
// 425.417 us; speedup vs baseline: 1.1873x; 1.1873x over previous
//
#include <hip/hip_runtime.h>

// ---------------------------------------------------------------------------
// MambaLatentBiMap: 2 branches (fwd / reversed) x 2 mamba layers + gates.
// Rows r = (j, b, l). Layer index for stage s, branch j: lidx = s + 2*j.
// MFMA GEMMs (gate, GEMM1, GEMM4): EXACT 3-way bf16 split (6 product terms ->
// fp32-equivalent), operands pre-split into 3 u16 planes by producers.
// Round-8 restructure: gemm stages operands with global_load_lds (width 16,
// no VGPR round-trip -- rounds 6/7 showed ~123 MB/dispatch of phantom HBM
// writes with register-prefetch staging). LDS = 6 linear [128][32]-u16 planes
// (48 KB, 3 blocks/CU). Bank conflicts on ds_read_b128 fixed by PRE-SWIZZLED
// global plane layout: element (row,k) stored at k ^= ((row>>1)&3)<<3; the
// gemm reads LDS chunk g ^ ((row>>1)&3). Producers and consumer share swzi().
// Scan: chunked linear recurrence, CL=32. Gate & GEMM4 K-split via grid.z.
// ---------------------------------------------------------------------------

#define LSEQ 1024
#define SCAN_CL 32
#define SCAN_NC 32

typedef short bf16x8 __attribute__((ext_vector_type(8)));
typedef float f32x4 __attribute__((ext_vector_type(4)));

__device__ __forceinline__ float sigmoidf_(float x) { return 1.f / (1.f + __expf(-x)); }
__device__ __forceinline__ float siluf_(float x)    { return x / (1.f + __expf(-x)); }
__device__ __forceinline__ float softplusf_(float x){ return x > 20.f ? x : log1pf(__expf(x)); }

__device__ __forceinline__ unsigned short bf16rne_(float v) {
  unsigned u = __float_as_uint(v);
  return (unsigned short)((u + 0x7FFFu + ((u >> 16) & 1u)) >> 16);
}
__device__ __forceinline__ float bfto_(unsigned short h) {
  return __uint_as_float(((unsigned)h) << 16);
}
__device__ __forceinline__ void split3_(float v, unsigned short& h,
                                        unsigned short& m, unsigned short& l) {
  h = bf16rne_(v); float r = v - bfto_(h);
  m = bf16rne_(r); float r2 = r - bfto_(m);
  l = bf16rne_(r2);
}

// swizzle: XOR k-bits 3-4 of a u16 plane index with row bits 1-2.
// Valid because every plane's K-dim is a multiple of 32 (k bits 3-4 stay
// inside the 32-element K-chunk). Producers write through this; the gemm's
// linear global_load_lds copy then lands data so that reading LDS chunk
// g ^ ((row>>1)&3) returns the true element (involution).
__device__ __forceinline__ long swzi(long idx, long row) {
  return idx ^ (((row >> 1) & 3) << 3);
}

// ---------------- prep: x (B,D,L) -> X planes rows (j,b,l) cols d ----------
__global__ __launch_bounds__(256) void prep_kernel(const float* __restrict__ x,
                                                   unsigned short* __restrict__ Xh,
                                                   unsigned short* __restrict__ Xm,
                                                   unsigned short* __restrict__ Xl) {
  long idx = (long)blockIdx.x * 256 + threadIdx.x;   // 2,097,152
  int d = (int)(idx & 255);
  long t = idx >> 8;
  int l = (int)(t & 1023);
  int t2 = (int)(t >> 10);
  int b = t2 & 3;
  int j = t2 >> 2;
  int lsrc = j ? (1023 - l) : l;
  float v = x[((long)(b * 256 + d)) * LSEQ + lsrc];
  long o = swzi(idx, t);               // row = t, K = 256
  split3_(v, Xh[o], Xm[o], Xl[o]);
}

// ---------------- Aneg = -exp(Alog) ----------------------------------------
__global__ __launch_bounds__(256) void aneg_kernel(const float* __restrict__ Alog,
                                                   float* __restrict__ Aneg) {
  int idx = blockIdx.x * 256 + threadIdx.x;          // 32768
  Aneg[idx] = -__expf(Alog[idx]);
}

// ---------------- elementwise 3-way split, K=1024 planes (x gate, Wg) ------
__global__ __launch_bounds__(256) void split3v_kernel(const float4* __restrict__ in,
                                                      unsigned short* __restrict__ oh,
                                                      unsigned short* __restrict__ om,
                                                      unsigned short* __restrict__ ol, int n4) {
  int i = blockIdx.x * 256 + threadIdx.x;
  if (i >= n4) return;
  float4 v = in[i];
  long b = 4L * i;                     // u16 base index; row = b >> 10 (K=1024)
  long sb = swzi(b, b >> 10);          // float4 stays inside one 8-u16 chunk
  ushort4 H, M, L;
  split3_(v.x, H.x, M.x, L.x); split3_(v.y, H.y, M.y, L.y);
  split3_(v.z, H.z, M.z, L.z); split3_(v.w, H.w, M.w, L.w);
  *(ushort4*)(oh + sb) = H; *(ushort4*)(om + sb) = M; *(ushort4*)(ol + sb) = L;
}

// ---------------- transpose + 3-way split: [Z][K][N] -> [Z][N][K] ----------
__global__ __launch_bounds__(256) void tconv3_kernel(const float* __restrict__ in,
                                                     unsigned short* __restrict__ oh,
                                                     unsigned short* __restrict__ om,
                                                     unsigned short* __restrict__ ol,
                                                     int K, int N) {
  __shared__ float T[32][33];
  int z = blockIdx.z;
  int n0 = blockIdx.x * 32, k0 = blockIdx.y * 32;
  int tx = threadIdx.x & 31, ty = threadIdx.x >> 5;   // 32 x 8
  const float* src = in + (long)z * K * N;
#pragma unroll
  for (int m = 0; m < 4; ++m)
    T[ty + 8 * m][tx] = src[(long)(k0 + ty + 8 * m) * N + n0 + tx];
  __syncthreads();
  long obase = (long)z * N * K;
#pragma unroll
  for (int m = 0; m < 4; ++m) {
    float v = T[tx][ty + 8 * m];
    int n = n0 + ty + 8 * m;
    long o = swzi(obase + (long)n * K + k0 + tx, n);
    split3_(v, oh[o], om[o], ol[o]);
  }
}

// ---------------- MFMA 3-split bf16 GEMM (global_load_lds staging) ---------
// C[bz](128x128 tiles of MxN) = A[z](M x lda) * B[z](N x ldb)^T over K-half.
// KSPLIT=2: bz = z*2 + kh, KH = K/2. KSPLIT=1: bz = z, KH = K.
// Operand planes are PRE-SWIZZLED in global memory (see swzi). Staging is a
// pure linear 16B-per-lane global_load_lds; fragment ds_reads apply the
// swizzle -> conflict-free. Output: plain f32 (partial if KSPLIT=2).
__device__ __forceinline__ void gload16(const unsigned short* g, unsigned short* l) {
  __builtin_amdgcn_global_load_lds(
      (const __attribute__((address_space(1))) unsigned int*)g,
      (__attribute__((address_space(3))) unsigned int*)l, 16, 0, 0);
}

template <int KSPLIT>
__global__ __launch_bounds__(256)
void gemm_mfma(const unsigned short* __restrict__ Ah_g,
               const unsigned short* __restrict__ Am_g,
               const unsigned short* __restrict__ Al_g, long aZ, int lda,
               const unsigned short* __restrict__ Bh_g,
               const unsigned short* __restrict__ Bm_g,
               const unsigned short* __restrict__ Bl_g, long bZ, int ldb,
               float* __restrict__ C, long cZ, int N, int KH) {
  __shared__ unsigned short S[6][128 * 32];   // Ah Am Al Bh Bm Bl, 48 KB
  const int bz = blockIdx.z;
  const int z  = (KSPLIT == 2) ? (bz >> 1) : bz;
  const int kh = (KSPLIT == 2) ? (bz & 1) : 0;
  const int m0 = blockIdx.y * 128, n0 = blockIdx.x * 128;
  const int tid = threadIdx.x;

  // staging: unit u in [0,512) per plane = (row u>>2, 16B-chunk u&3);
  // thread tid handles u=tid and u=tid+256. LDS dest = u*16 bytes (linear).
  const long khoff = (long)kh * KH;
  const long a0 = (long)z * aZ + (long)(m0 + (tid >> 2)) * lda + khoff + (tid & 3) * 8;
  const long a1 = a0 + 64L * lda;
  const long b0 = (long)z * bZ + (long)(n0 + (tid >> 2)) * ldb + khoff + (tid & 3) * 8;
  const long b1 = b0 + 64L * ldb;
  const int l0 = tid * 8, l1 = tid * 8 + 2048;   // u16 offsets into S[p]

  const int lane = tid & 63, w = tid >> 6;
  const int wr = w >> 1, wc = w & 1;
  const int fr = lane & 15, g = lane >> 4;

  f32x4 acc[4][4];
#pragma unroll
  for (int i = 0; i < 4; ++i)
#pragma unroll
    for (int j = 0; j < 4; ++j)
#pragma unroll
      for (int q = 0; q < 4; ++q) acc[i][j][q] = 0.f;

  for (int k0 = 0; k0 < KH; k0 += 32) {
    __syncthreads();   // protect LDS from readers of previous iteration
    gload16(Ah_g + a0 + k0, &S[0][l0]); gload16(Ah_g + a1 + k0, &S[0][l1]);
    gload16(Am_g + a0 + k0, &S[1][l0]); gload16(Am_g + a1 + k0, &S[1][l1]);
    gload16(Al_g + a0 + k0, &S[2][l0]); gload16(Al_g + a1 + k0, &S[2][l1]);
    gload16(Bh_g + b0 + k0, &S[3][l0]); gload16(Bh_g + b1 + k0, &S[3][l1]);
    gload16(Bm_g + b0 + k0, &S[4][l0]); gload16(Bm_g + b1 + k0, &S[4][l1]);
    gload16(Bl_g + b0 + k0, &S[5][l0]); gload16(Bl_g + b1 + k0, &S[5][l1]);
    __syncthreads();   // drains vmcnt -> staged data visible

    bf16x8 fb[3][4];
#pragma unroll
    for (int nf = 0; nf < 4; ++nf) {
      int rb = wc * 64 + nf * 16 + fr;
      int ob = rb * 32 + ((g ^ ((rb >> 1) & 3)) << 3);
      fb[0][nf] = *(const bf16x8*)&S[3][ob];
      fb[1][nf] = *(const bf16x8*)&S[4][ob];
      fb[2][nf] = *(const bf16x8*)&S[5][ob];
    }
#pragma unroll
    for (int mf = 0; mf < 4; ++mf) {
      int ra = wr * 64 + mf * 16 + fr;
      int oa = ra * 32 + ((g ^ ((ra >> 1) & 3)) << 3);
      bf16x8 fah = *(const bf16x8*)&S[0][oa];
      bf16x8 fam = *(const bf16x8*)&S[1][oa];
      bf16x8 fal = *(const bf16x8*)&S[2][oa];
#pragma unroll
      for (int nf = 0; nf < 4; ++nf) {
        acc[mf][nf] = __builtin_amdgcn_mfma_f32_16x16x32_bf16(fah, fb[0][nf], acc[mf][nf], 0, 0, 0);
        acc[mf][nf] = __builtin_amdgcn_mfma_f32_16x16x32_bf16(fah, fb[1][nf], acc[mf][nf], 0, 0, 0);
        acc[mf][nf] = __builtin_amdgcn_mfma_f32_16x16x32_bf16(fam, fb[0][nf], acc[mf][nf], 0, 0, 0);
        acc[mf][nf] = __builtin_amdgcn_mfma_f32_16x16x32_bf16(fam, fb[1][nf], acc[mf][nf], 0, 0, 0);
        acc[mf][nf] = __builtin_amdgcn_mfma_f32_16x16x32_bf16(fah, fb[2][nf], acc[mf][nf], 0, 0, 0);
        acc[mf][nf] = __builtin_amdgcn_mfma_f32_16x16x32_bf16(fal, fb[0][nf], acc[mf][nf], 0, 0, 0);
      }
    }
  }

  float* Cz = C + (long)bz * cZ;
#pragma unroll
  for (int mf = 0; mf < 4; ++mf)
#pragma unroll
    for (int nf = 0; nf < 4; ++nf) {
      int col = n0 + wc * 64 + nf * 16 + fr;
      int row0 = m0 + wr * 64 + mf * 16 + g * 4;
#pragma unroll
      for (int q = 0; q < 4; ++q)
        Cz[(long)(row0 + q) * N + col] = acc[mf][nf][q];
    }
}

// ---------------- combine2: sum two K-split partial planes + epilogue ------
// OP: 0 plain f32, 1 sigmoid(v + bias), 2 split3 -> swizzled planes (K=256)
template <int OP>
__global__ __launch_bounds__(256)
void combine2_kernel(const float* __restrict__ P, long pz,
                     const float* __restrict__ bias, int nmask,
                     float* __restrict__ outF,
                     unsigned short* __restrict__ oh,
                     unsigned short* __restrict__ om,
                     unsigned short* __restrict__ ol, long oz) {
  int z = blockIdx.y;
  long i = (long)blockIdx.x * 256 + threadIdx.x;
  float v = P[(long)(2 * z) * pz + i] + P[(long)(2 * z + 1) * pz + i];
  if (OP == 1) {
    outF[(long)z * oz + i] = sigmoidf_(v + bias[z * (nmask + 1) + (int)(i & nmask)]);
  } else if (OP == 0) {
    outF[(long)z * oz + i] = v;
  } else {
    long o = (long)z * oz + swzi(i, i >> 8);   // row = i>>8, K = 256
    split3_(v, oh[o], om[o], ol[o]);
  }
}

// ---------------- generic tiled fp32 GEMM (GEMM2, GEMM3) -------------------
template <int EPI>   // 0 none, 1 bias+softplus
__global__ __launch_bounds__(256)
void gemm_f32(const float* __restrict__ A, int lda, long aZ,
              const float* __restrict__ W, int ldw, long wZ,
              const float* __restrict__ Bias, long bZ,
              float* __restrict__ C, int ldc, long cZ,
              int M, int N, int K) {
  constexpr int BM = 128, BN = 64, BK = 16;
  __shared__ __align__(16) float As[BK][BM];
  __shared__ __align__(16) float Bs[BK][BN];
  const int z = blockIdx.z;
  A += (long)z * aZ;
  W += (long)z * wZ;
  C += (long)z * cZ;
  const float* bias = (EPI != 0) ? (Bias + (long)z * bZ) : nullptr;
  const int m0 = blockIdx.y * BM, n0 = blockIdx.x * BN;
  const int tid = threadIdx.x;
  const int tx = tid & 15, ty = tid >> 4;

  float acc[8][4];
#pragma unroll
  for (int i = 0; i < 8; ++i)
#pragma unroll
    for (int jn = 0; jn < 4; ++jn) acc[i][jn] = 0.f;

  for (int k0 = 0; k0 < K; k0 += BK) {
#pragma unroll
    for (int i = 0; i < 2; ++i) {
      int idx = tid + i * 256;
      int m = idx >> 2, k4 = (idx & 3) << 2;
      float4 v = *(const float4*)(A + (long)(m0 + m) * lda + k0 + k4);
      As[k4 + 0][m] = v.x; As[k4 + 1][m] = v.y;
      As[k4 + 2][m] = v.z; As[k4 + 3][m] = v.w;
    }
    {
      int k = tid >> 4, n4 = (tid & 15) << 2;
      float4 v = make_float4(0.f, 0.f, 0.f, 0.f);
      if (n0 + n4 < N) v = *(const float4*)(W + (long)(k0 + k) * ldw + n0 + n4);
      Bs[k][n4 + 0] = v.x; Bs[k][n4 + 1] = v.y;
      Bs[k][n4 + 2] = v.z; Bs[k][n4 + 3] = v.w;
    }
    __syncthreads();
#pragma unroll
    for (int kk = 0; kk < BK; ++kk) {
      float a[8], bb[4];
#pragma unroll
      for (int i = 0; i < 8; ++i) a[i] = As[kk][ty * 8 + i];
#pragma unroll
      for (int jn = 0; jn < 4; ++jn) bb[jn] = Bs[kk][tx * 4 + jn];
#pragma unroll
      for (int i = 0; i < 8; ++i)
#pragma unroll
        for (int jn = 0; jn < 4; ++jn) acc[i][jn] = fmaf(a[i], bb[jn], acc[i][jn]);
    }
    __syncthreads();
  }

  int n = n0 + tx * 4;
  if (n < N) {
#pragma unroll
    for (int i = 0; i < 8; ++i) {
      int m = m0 + ty * 8 + i;
      float4 v;
      float* vp = &v.x;
#pragma unroll
      for (int jn = 0; jn < 4; ++jn) {
        float val = acc[i][jn];
        if (EPI) val += bias[n + jn];
        if (EPI == 1) val = softplusf_(val);
        vp[jn] = val;
      }
      *(float4*)(C + (long)m * ldc + n) = v;
    }
  }
}

// ---------------- causal conv4 + silu --------------------------------------
__global__ __launch_bounds__(256) void conv_kernel(const float* __restrict__ UZ,
                                                   const float* __restrict__ Wconv,
                                                   const float* __restrict__ bconv,
                                                   float* __restrict__ uc, int stage) {
  long idx = (long)blockIdx.x * 256 + threadIdx.x;  // 8192*256
  int di = (int)(idx & 255);
  long r = idx >> 8;
  int l = (int)(r & 1023);
  int j = (int)(r >> 12);
  int lidx = stage + 2 * j;
  const float* wc = Wconv + (long)(lidx * 256 + di) * 4;
  float acc = bconv[lidx * 256 + di];
  const float* up = UZ + (r - 3) * 512 + di;
  if (l >= 3) {
    acc = fmaf(up[0], wc[0], acc);
    acc = fmaf(up[512], wc[1], acc);
    acc = fmaf(up[1024], wc[2], acc);
    acc = fmaf(up[1536], wc[3], acc);
  } else {
    for (int k = 3 - l; k < 4; ++k) acc = fmaf(up[(long)k * 512], wc[k], acc);
  }
  uc[idx] = acc * sigmoidf_(acc);
}

// ---------------- selective scan: chunked (CL=32) --------------------------
template <int PASS>
__global__ __launch_bounds__(256)
void scan_chunk_kernel(const float* __restrict__ dt,
                       const float* __restrict__ uc,
                       const float* __restrict__ UZ,
                       const float* __restrict__ proj,
                       const float* __restrict__ Aneg,
                       const float* __restrict__ Dskip,
                       float* __restrict__ HST,   // [8][NC][256][32]
                       float* __restrict__ DTS,   // [8][NC][256]
                       unsigned short* __restrict__ YGh,
                       unsigned short* __restrict__ YGm,
                       unsigned short* __restrict__ YGl, int stage) {
  __shared__ __align__(16) float BC[SCAN_CL][64];
  const int blk = blockIdx.x;
  const int chunk = blk & (SCAN_NC - 1);
  const int jb = blk >> 5;
  const int di = threadIdx.x;
  const int j = jb >> 2;
  const int lidx = stage + 2 * j;
  const long r0 = (long)jb * 1024 + (long)chunk * SCAN_CL;

  for (int e = threadIdx.x; e < SCAN_CL * 64; e += 256) {
    int l = e >> 6, col = e & 63;
    BC[l][col] = proj[(r0 + l) * 80 + 16 + col];
  }

  float A[32];
  {
    const float4* ap = (const float4*)(Aneg + ((long)(lidx * 256 + di)) * 32);
#pragma unroll
    for (int q = 0; q < 8; ++q) {
      float4 v = ap[q];
      A[4 * q] = v.x; A[4 * q + 1] = v.y; A[4 * q + 2] = v.z; A[4 * q + 3] = v.w;
    }
  }

  const long sbase = (((long)jb * SCAN_NC + chunk) * 256 + di) * 32;
  float h[32];
  if (PASS == 0) {
#pragma unroll
    for (int n = 0; n < 32; ++n) h[n] = 0.f;
  } else {
    const float4* hp = (const float4*)(HST + sbase);
#pragma unroll
    for (int q = 0; q < 8; ++q) {
      float4 v = hp[q];
      h[4 * q] = v.x; h[4 * q + 1] = v.y; h[4 * q + 2] = v.z; h[4 * q + 3] = v.w;
    }
  }

  float Dsk = 0.f, dtsum = 0.f;
  if (PASS == 1) Dsk = Dskip[lidx * 256 + di];

  __syncthreads();

  for (int l = 0; l < SCAN_CL; ++l) {
    const long r = r0 + l;
    float dtv = dt[r * 256 + di];
    float uv  = uc[r * 256 + di];
    float du  = dtv * uv;
    if (PASS == 0) dtsum += dtv;
    float yacc[4] = {0.f, 0.f, 0.f, 0.f};
    const float4* bc4 = (const float4*)&BC[l][0];
#pragma unroll
    for (int q = 0; q < 8; ++q) {
      float4 bv = bc4[q];
      float4 cv = bc4[8 + q];
      const float* bp = &bv.x;
      const float* cp = &cv.x;
#pragma unroll
      for (int k = 0; k < 4; ++k) {
        int n = 4 * q + k;
        float a = __expf(dtv * A[n]);
        h[n] = fmaf(a, h[n], du * bp[k]);
        yacc[n & 3] = fmaf(h[n], cp[k], yacc[n & 3]);
      }
    }
    if (PASS == 1) {
      float y = (yacc[0] + yacc[1]) + (yacc[2] + yacc[3]);
      float zv = UZ[r * 512 + 256 + di];
      float val = (y + uv * Dsk) * siluf_(zv);
      long o = swzi(r * 256 + di, r);   // swizzled YG planes (K=256)
      split3_(val, YGh[o], YGm[o], YGl[o]);
    }
  }

  if (PASS == 0) {
    float4* hp = (float4*)(HST + sbase);
#pragma unroll
    for (int q = 0; q < 8; ++q)
      hp[q] = make_float4(h[4 * q], h[4 * q + 1], h[4 * q + 2], h[4 * q + 3]);
    DTS[((long)jb * SCAN_NC + chunk) * 256 + di] = dtsum;
  }
}

// ---------------- scan pass 2: sequential chunk combine --------------------
__global__ __launch_bounds__(256)
void scan_combine_kernel(float* __restrict__ HST, const float* __restrict__ DTS,
                         const float* __restrict__ Aneg, int stage) {
  int t = blockIdx.x * 256 + threadIdx.x;   // 65536
  int n = t & 31;
  int di = (t >> 5) & 255;
  int jb = t >> 13;
  int lidx = stage + 2 * (jb >> 2);
  float A = Aneg[((long)(lidx * 256 + di)) * 32 + n];
  float hs = 0.f;
  for (int c = 0; c < SCAN_NC; ++c) {
    long base = ((long)jb * SCAN_NC + c) * 256 + di;
    long idx = base * 32 + n;
    float s = HST[idx];
    HST[idx] = hs;
    float P = __expf(A * DTS[base]);
    hs = fmaf(P, hs, s);
  }
}

// ---------------- final combine --------------------------------------------
__global__ __launch_bounds__(256) void combine_kernel(const float* __restrict__ H,
                                                      const float* __restrict__ gate,
                                                      const float* __restrict__ alpha,
                                                      const float* __restrict__ gamma,
                                                      const float* __restrict__ beta,
                                                      float* __restrict__ out) {
  long idx = (long)blockIdx.x * 256 + threadIdx.x;  // 1,048,576 (b,d,l)
  int l = (int)(idx & 1023);
  long t = idx >> 10;
  int d = (int)(t & 255);
  int b = (int)(t >> 8);
  int lr = 1023 - l;
  float h0 = H[(((long)b * 1024 + l) * 256) + d];
  float h1 = H[(((long)(4 + b) * 1024 + lr) * 256) + d];
  float g0 = gate[((long)(b * 256 + d)) * 1024 + l];
  float g1 = gate[(long)1024 * 1024 + ((long)(b * 256 + d)) * 1024 + lr];
  float m0 = (gamma[l] * tanhf(alpha[0] * h0) + beta[l]) * g0;
  float m1 = (gamma[1024 + lr] * tanhf(alpha[1] * h1) + beta[1024 + lr]) * g1;
  out[idx] = m0 + m1;
}

// ---------------------------------------------------------------------------
extern "C" void kernel_launch(void* const* d_in, const int* in_sizes, int n_in,
                              void* d_out, int out_size, void* d_ws, size_t ws_size,
                              hipStream_t stream) {
  const float* x     = (const float*)d_in[0];
  const float* Win   = (const float*)d_in[1];
  const float* Wconv = (const float*)d_in[2];
  const float* bconv = (const float*)d_in[3];
  const float* Wxp   = (const float*)d_in[4];
  const float* Wdt   = (const float*)d_in[5];
  const float* bdt   = (const float*)d_in[6];
  const float* Alog  = (const float*)d_in[7];
  const float* Dskip = (const float*)d_in[8];
  const float* Wout  = (const float*)d_in[9];
  const float* Wg    = (const float*)d_in[10];
  const float* bg    = (const float*)d_in[11];
  const float* alpha = (const float*)d_in[12];
  const float* gamma = (const float*)d_in[13];
  const float* beta  = (const float*)d_in[14];
  float* out = (float*)d_out;

  // ---- workspace layout (floats); total 20,873,216 f = 83.5 MB ----
  float* ws   = (float*)d_ws;
  float* UZ   = ws;                    // 4,194,304 f
  float* UC   = UZ + 4194304;          // 2,097,152 f
  float* PROJ = UC + 2097152;          // 655,360 f
  float* DT   = PROJ + 655360;         // 2,097,152 f
  float* GATE = DT + 2097152;          // 2,097,152 f
  float* ANEG = GATE + 2097152;        // 32,768 f
  float* HST  = ANEG + 32768;          // 2,097,152 f
  float* DTS  = HST + 2097152;         // 131,072 f
  unsigned short* Xpl  = (unsigned short*)(DTS + 131072);   // 3 x 2,097,152 u16
  unsigned short* YGpl = Xpl + 3 * 2097152;                 // 3 x 2,097,152 u16
  unsigned short* WinT = YGpl + 3 * 2097152;                // 3 x 524,288 u16
  unsigned short* WoutT = WinT + 3 * 524288;                // 3 x 262,144 u16
  // aliases
  float* PG  = UC;                          // 4 x 1,048,576 f partials
  float* XF  = UZ;                          // final H (stage-1 GEMM4 out)
  unsigned short* XGh = (unsigned short*)GATE;   // 3 x 1,048,576 u16
  unsigned short* XGm = XGh + 1048576;
  unsigned short* XGl = XGm + 1048576;
  unsigned short* Wgh = YGpl;                    // 3 x 2,097,152 u16
  unsigned short* Wgm = Wgh + 2097152;
  unsigned short* Wgl = Wgm + 2097152;
  unsigned short* Xh = Xpl, *Xm = Xpl + 2097152, *Xl = Xpl + 2 * 2097152;
  unsigned short* YGh = YGpl, *YGm = YGpl + 2097152, *YGl = YGpl + 2 * 2097152;
  unsigned short* WinTh = WinT, *WinTm = WinT + 524288, *WinTl = WinT + 2 * 524288;
  unsigned short* WoutTh = WoutT, *WoutTm = WoutT + 262144, *WoutTl = WoutT + 2 * 262144;

  // ---- prep / weight splitting (all planes written PRE-SWIZZLED) ----
  prep_kernel<<<dim3(8192), dim3(256), 0, stream>>>(x, Xh, Xm, Xl);
  aneg_kernel<<<dim3(128), dim3(256), 0, stream>>>(Alog, ANEG);
  split3v_kernel<<<dim3(1024), dim3(256), 0, stream>>>(
      (const float4*)x, XGh, XGm, XGl, 262144);
  split3v_kernel<<<dim3(2048), dim3(256), 0, stream>>>(
      (const float4*)Wg, Wgh, Wgm, Wgl, 524288);
  tconv3_kernel<<<dim3(16, 8, 4), dim3(256), 0, stream>>>(Win, WinTh, WinTm, WinTl, 256, 512);
  tconv3_kernel<<<dim3(8, 8, 4), dim3(256), 0, stream>>>(Wout, WoutTh, WoutTm, WoutTl, 256, 256);

  // ---- gate: PG[z*2+kh] = x @ Wg[z]^T (K-half kh); GATE = sigmoid(sum+bg) ----
  gemm_mfma<2><<<dim3(8, 8, 4), dim3(256), 0, stream>>>(
      XGh, XGm, XGl, 0L, 1024,
      Wgh, Wgm, Wgl, (long)1024 * 1024, 1024,
      PG, (long)1024 * 1024, 1024, 512);
  combine2_kernel<1><<<dim3(4096, 2), dim3(256), 0, stream>>>(
      PG, (long)1024 * 1024, bg, 1023, GATE, nullptr, nullptr, nullptr,
      (long)1024 * 1024);

  for (int s = 0; s < 2; ++s) {
    // GEMM1: UZ = X @ Win[lidx]  (N=512, K=256)
    gemm_mfma<1><<<dim3(4, 32, 2), dim3(256), 0, stream>>>(
        Xh, Xm, Xl, (long)4096 * 256, 256,
        WinTh + (long)s * 131072, WinTm + (long)s * 131072, WinTl + (long)s * 131072,
        (long)262144, 256,
        UZ, (long)4096 * 512, 512, 256);

    conv_kernel<<<dim3(8192), dim3(256), 0, stream>>>(UZ, Wconv, bconv, UC, s);

    // GEMM2: PROJ = UC @ Wxp[lidx] (N=80, fp32)
    gemm_f32<0><<<dim3(2, 32, 2), dim3(256), 0, stream>>>(
        UC, 256, (long)4096 * 256, Wxp + (long)s * 256 * 80, 80, (long)2 * 256 * 80,
        nullptr, 0, PROJ, 80, (long)4096 * 80, 4096, 80, 256);

    // GEMM3: DT = softplus(PROJ[:, :16] @ Wdt[lidx] + bdt[lidx])
    gemm_f32<1><<<dim3(4, 32, 2), dim3(256), 0, stream>>>(
        PROJ, 80, (long)4096 * 80, Wdt + (long)s * 16 * 256, 256, (long)2 * 16 * 256,
        bdt + s * 256, 512, DT, 256, (long)4096 * 256, 4096, 256, 16);

    // chunked selective scan (pass1 writes swizzled YG planes)
    scan_chunk_kernel<0><<<dim3(8 * SCAN_NC), dim3(256), 0, stream>>>(
        DT, UC, UZ, PROJ, ANEG, Dskip, HST, DTS, YGh, YGm, YGl, s);
    scan_combine_kernel<<<dim3(256), dim3(256), 0, stream>>>(HST, DTS, ANEG, s);
    scan_chunk_kernel<1><<<dim3(8 * SCAN_NC), dim3(256), 0, stream>>>(
        DT, UC, UZ, PROJ, ANEG, Dskip, HST, DTS, YGh, YGm, YGl, s);

    // GEMM4 (K-split): PG[z*2+kh] = YG @ Wout[lidx] (K-half), then combine
    gemm_mfma<2><<<dim3(2, 32, 4), dim3(256), 0, stream>>>(
        YGh, YGm, YGl, (long)4096 * 256, 256,
        WoutTh + (long)s * 65536, WoutTm + (long)s * 65536, WoutTl + (long)s * 65536,
        (long)131072, 256,
        PG, (long)4096 * 256, 256, 128);
    if (s == 0) {
      combine2_kernel<2><<<dim3(4096, 2), dim3(256), 0, stream>>>(
          PG, (long)4096 * 256, nullptr, 0, nullptr, Xh, Xm, Xl, (long)4096 * 256);
    } else {
      combine2_kernel<0><<<dim3(4096, 2), dim3(256), 0, stream>>>(
          PG, (long)4096 * 256, nullptr, 0, XF, nullptr, nullptr, nullptr,
          (long)4096 * 256);
    }
  }

  combine_kernel<<<dim3(4096), dim3(256), 0, stream>>>(XF, GATE, alpha, gamma, beta, out);
}

// Round 9
// 381.228 us; speedup vs baseline: 1.3250x; 1.1159x over previous
//
#include <hip/hip_runtime.h>

// ---------------------------------------------------------------------------
// MambaLatentBiMap: 2 branches (fwd / reversed) x 2 mamba layers + gates.
// Rows r = (j, b, l). Layer index for stage s, branch j: lidx = s + 2*j.
// MFMA GEMMs (gate, GEMM1, GEMM4): EXACT 3-way bf16 split (6 product terms ->
// fp32-equivalent), operands pre-split into 3 u16 planes by producers.
// gemm stages via global_load_lds (width 16); bank conflicts fixed by
// PRE-SWIZZLED global plane layout (swzi: k ^= ((row>>1)&3)<<3, involution).
// Scan: chunked linear recurrence CL=32; round-9: batched double-buffered
// register loads (8-column batches -- 1 wave/SIMD cannot hide per-step load
// latency; round-8 counters: VALUBusy 26%, 46 us vs ~4 us compute) and
// exp2 with pre-scaled A (ANEG holds -exp(Alog)*log2e).
// ---------------------------------------------------------------------------

#define LSEQ 1024
#define SCAN_CL 32
#define SCAN_NC 32

#if __has_builtin(__builtin_amdgcn_exp2f)
#define EXP2(x) __builtin_amdgcn_exp2f(x)
#else
#define EXP2(x) exp2f(x)
#endif

typedef short bf16x8 __attribute__((ext_vector_type(8)));
typedef float f32x4 __attribute__((ext_vector_type(4)));

__device__ __forceinline__ float sigmoidf_(float x) { return 1.f / (1.f + __expf(-x)); }
__device__ __forceinline__ float siluf_(float x)    { return x / (1.f + __expf(-x)); }
__device__ __forceinline__ float softplusf_(float x){ return x > 20.f ? x : log1pf(__expf(x)); }

__device__ __forceinline__ unsigned short bf16rne_(float v) {
  unsigned u = __float_as_uint(v);
  return (unsigned short)((u + 0x7FFFu + ((u >> 16) & 1u)) >> 16);
}
__device__ __forceinline__ float bfto_(unsigned short h) {
  return __uint_as_float(((unsigned)h) << 16);
}
__device__ __forceinline__ void split3_(float v, unsigned short& h,
                                        unsigned short& m, unsigned short& l) {
  h = bf16rne_(v); float r = v - bfto_(h);
  m = bf16rne_(r); float r2 = r - bfto_(m);
  l = bf16rne_(r2);
}

// swizzle: XOR k-bits 3-4 of a u16 plane index with row bits 1-2 (involution;
// valid since every plane K-dim is a multiple of 32).
__device__ __forceinline__ long swzi(long idx, long row) {
  return idx ^ (((row >> 1) & 3) << 3);
}

// ---------------- prep: x (B,D,L) -> X planes rows (j,b,l) cols d ----------
__global__ __launch_bounds__(256) void prep_kernel(const float* __restrict__ x,
                                                   unsigned short* __restrict__ Xh,
                                                   unsigned short* __restrict__ Xm,
                                                   unsigned short* __restrict__ Xl) {
  long idx = (long)blockIdx.x * 256 + threadIdx.x;   // 2,097,152
  int d = (int)(idx & 255);
  long t = idx >> 8;
  int l = (int)(t & 1023);
  int t2 = (int)(t >> 10);
  int b = t2 & 3;
  int j = t2 >> 2;
  int lsrc = j ? (1023 - l) : l;
  float v = x[((long)(b * 256 + d)) * LSEQ + lsrc];
  long o = swzi(idx, t);               // row = t, K = 256
  split3_(v, Xh[o], Xm[o], Xl[o]);
}

// ---------------- Aneg2 = -exp(Alog) * log2(e) -----------------------------
__global__ __launch_bounds__(256) void aneg_kernel(const float* __restrict__ Alog,
                                                   float* __restrict__ Aneg) {
  int idx = blockIdx.x * 256 + threadIdx.x;          // 32768
  Aneg[idx] = -__expf(Alog[idx]) * 1.4426950408889634f;
}

// ---------------- elementwise 3-way split, K=1024 planes (x gate, Wg) ------
__global__ __launch_bounds__(256) void split3v_kernel(const float4* __restrict__ in,
                                                      unsigned short* __restrict__ oh,
                                                      unsigned short* __restrict__ om,
                                                      unsigned short* __restrict__ ol, int n4) {
  int i = blockIdx.x * 256 + threadIdx.x;
  if (i >= n4) return;
  float4 v = in[i];
  long b = 4L * i;                     // u16 base index; row = b >> 10 (K=1024)
  long sb = swzi(b, b >> 10);          // float4 stays inside one 8-u16 chunk
  ushort4 H, M, L;
  split3_(v.x, H.x, M.x, L.x); split3_(v.y, H.y, M.y, L.y);
  split3_(v.z, H.z, M.z, L.z); split3_(v.w, H.w, M.w, L.w);
  *(ushort4*)(oh + sb) = H; *(ushort4*)(om + sb) = M; *(ushort4*)(ol + sb) = L;
}

// ---------------- transpose + 3-way split: [Z][K][N] -> [Z][N][K] ----------
__global__ __launch_bounds__(256) void tconv3_kernel(const float* __restrict__ in,
                                                     unsigned short* __restrict__ oh,
                                                     unsigned short* __restrict__ om,
                                                     unsigned short* __restrict__ ol,
                                                     int K, int N) {
  __shared__ float T[32][33];
  int z = blockIdx.z;
  int n0 = blockIdx.x * 32, k0 = blockIdx.y * 32;
  int tx = threadIdx.x & 31, ty = threadIdx.x >> 5;   // 32 x 8
  const float* src = in + (long)z * K * N;
#pragma unroll
  for (int m = 0; m < 4; ++m)
    T[ty + 8 * m][tx] = src[(long)(k0 + ty + 8 * m) * N + n0 + tx];
  __syncthreads();
  long obase = (long)z * N * K;
#pragma unroll
  for (int m = 0; m < 4; ++m) {
    float v = T[tx][ty + 8 * m];
    int n = n0 + ty + 8 * m;
    long o = swzi(obase + (long)n * K + k0 + tx, n);
    split3_(v, oh[o], om[o], ol[o]);
  }
}

// ---------------- MFMA 3-split bf16 GEMM (global_load_lds staging) ---------
__device__ __forceinline__ void gload16(const unsigned short* g, unsigned short* l) {
  __builtin_amdgcn_global_load_lds(
      (const __attribute__((address_space(1))) unsigned int*)g,
      (__attribute__((address_space(3))) unsigned int*)l, 16, 0, 0);
}

template <int KSPLIT>
__global__ __launch_bounds__(256)
void gemm_mfma(const unsigned short* __restrict__ Ah_g,
               const unsigned short* __restrict__ Am_g,
               const unsigned short* __restrict__ Al_g, long aZ, int lda,
               const unsigned short* __restrict__ Bh_g,
               const unsigned short* __restrict__ Bm_g,
               const unsigned short* __restrict__ Bl_g, long bZ, int ldb,
               float* __restrict__ C, long cZ, int N, int KH) {
  __shared__ unsigned short S[6][128 * 32];   // Ah Am Al Bh Bm Bl, 48 KB
  const int bz = blockIdx.z;
  const int z  = (KSPLIT == 2) ? (bz >> 1) : bz;
  const int kh = (KSPLIT == 2) ? (bz & 1) : 0;
  const int m0 = blockIdx.y * 128, n0 = blockIdx.x * 128;
  const int tid = threadIdx.x;

  const long khoff = (long)kh * KH;
  const long a0 = (long)z * aZ + (long)(m0 + (tid >> 2)) * lda + khoff + (tid & 3) * 8;
  const long a1 = a0 + 64L * lda;
  const long b0 = (long)z * bZ + (long)(n0 + (tid >> 2)) * ldb + khoff + (tid & 3) * 8;
  const long b1 = b0 + 64L * ldb;
  const int l0 = tid * 8, l1 = tid * 8 + 2048;   // u16 offsets into S[p]

  const int lane = tid & 63, w = tid >> 6;
  const int wr = w >> 1, wc = w & 1;
  const int fr = lane & 15, g = lane >> 4;

  f32x4 acc[4][4];
#pragma unroll
  for (int i = 0; i < 4; ++i)
#pragma unroll
    for (int j = 0; j < 4; ++j)
#pragma unroll
      for (int q = 0; q < 4; ++q) acc[i][j][q] = 0.f;

  for (int k0 = 0; k0 < KH; k0 += 32) {
    __syncthreads();   // protect LDS from readers of previous iteration
    gload16(Ah_g + a0 + k0, &S[0][l0]); gload16(Ah_g + a1 + k0, &S[0][l1]);
    gload16(Am_g + a0 + k0, &S[1][l0]); gload16(Am_g + a1 + k0, &S[1][l1]);
    gload16(Al_g + a0 + k0, &S[2][l0]); gload16(Al_g + a1 + k0, &S[2][l1]);
    gload16(Bh_g + b0 + k0, &S[3][l0]); gload16(Bh_g + b1 + k0, &S[3][l1]);
    gload16(Bm_g + b0 + k0, &S[4][l0]); gload16(Bm_g + b1 + k0, &S[4][l1]);
    gload16(Bl_g + b0 + k0, &S[5][l0]); gload16(Bl_g + b1 + k0, &S[5][l1]);
    __syncthreads();   // drains vmcnt -> staged data visible

    bf16x8 fb[3][4];
#pragma unroll
    for (int nf = 0; nf < 4; ++nf) {
      int rb = wc * 64 + nf * 16 + fr;
      int ob = rb * 32 + ((g ^ ((rb >> 1) & 3)) << 3);
      fb[0][nf] = *(const bf16x8*)&S[3][ob];
      fb[1][nf] = *(const bf16x8*)&S[4][ob];
      fb[2][nf] = *(const bf16x8*)&S[5][ob];
    }
#pragma unroll
    for (int mf = 0; mf < 4; ++mf) {
      int ra = wr * 64 + mf * 16 + fr;
      int oa = ra * 32 + ((g ^ ((ra >> 1) & 3)) << 3);
      bf16x8 fah = *(const bf16x8*)&S[0][oa];
      bf16x8 fam = *(const bf16x8*)&S[1][oa];
      bf16x8 fal = *(const bf16x8*)&S[2][oa];
#pragma unroll
      for (int nf = 0; nf < 4; ++nf) {
        acc[mf][nf] = __builtin_amdgcn_mfma_f32_16x16x32_bf16(fah, fb[0][nf], acc[mf][nf], 0, 0, 0);
        acc[mf][nf] = __builtin_amdgcn_mfma_f32_16x16x32_bf16(fah, fb[1][nf], acc[mf][nf], 0, 0, 0);
        acc[mf][nf] = __builtin_amdgcn_mfma_f32_16x16x32_bf16(fam, fb[0][nf], acc[mf][nf], 0, 0, 0);
        acc[mf][nf] = __builtin_amdgcn_mfma_f32_16x16x32_bf16(fam, fb[1][nf], acc[mf][nf], 0, 0, 0);
        acc[mf][nf] = __builtin_amdgcn_mfma_f32_16x16x32_bf16(fah, fb[2][nf], acc[mf][nf], 0, 0, 0);
        acc[mf][nf] = __builtin_amdgcn_mfma_f32_16x16x32_bf16(fal, fb[0][nf], acc[mf][nf], 0, 0, 0);
      }
    }
  }

  float* Cz = C + (long)bz * cZ;
#pragma unroll
  for (int mf = 0; mf < 4; ++mf)
#pragma unroll
    for (int nf = 0; nf < 4; ++nf) {
      int col = n0 + wc * 64 + nf * 16 + fr;
      int row0 = m0 + wr * 64 + mf * 16 + g * 4;
#pragma unroll
      for (int q = 0; q < 4; ++q)
        Cz[(long)(row0 + q) * N + col] = acc[mf][nf][q];
    }
}

// ---------------- combine2: sum two K-split partial planes + epilogue ------
// OP: 0 plain f32, 1 sigmoid(v + bias), 2 split3 -> swizzled planes (K=256)
template <int OP>
__global__ __launch_bounds__(256)
void combine2_kernel(const float* __restrict__ P, long pz,
                     const float* __restrict__ bias, int nmask,
                     float* __restrict__ outF,
                     unsigned short* __restrict__ oh,
                     unsigned short* __restrict__ om,
                     unsigned short* __restrict__ ol, long oz) {
  int z = blockIdx.y;
  long i = (long)blockIdx.x * 256 + threadIdx.x;
  float v = P[(long)(2 * z) * pz + i] + P[(long)(2 * z + 1) * pz + i];
  if (OP == 1) {
    outF[(long)z * oz + i] = sigmoidf_(v + bias[z * (nmask + 1) + (int)(i & nmask)]);
  } else if (OP == 0) {
    outF[(long)z * oz + i] = v;
  } else {
    long o = (long)z * oz + swzi(i, i >> 8);   // row = i>>8, K = 256
    split3_(v, oh[o], om[o], ol[o]);
  }
}

// ---------------- generic tiled fp32 GEMM (GEMM2, GEMM3) -------------------
template <int EPI>   // 0 none, 1 bias+softplus
__global__ __launch_bounds__(256)
void gemm_f32(const float* __restrict__ A, int lda, long aZ,
              const float* __restrict__ W, int ldw, long wZ,
              const float* __restrict__ Bias, long bZ,
              float* __restrict__ C, int ldc, long cZ,
              int M, int N, int K) {
  constexpr int BM = 128, BN = 64, BK = 16;
  __shared__ __align__(16) float As[BK][BM];
  __shared__ __align__(16) float Bs[BK][BN];
  const int z = blockIdx.z;
  A += (long)z * aZ;
  W += (long)z * wZ;
  C += (long)z * cZ;
  const float* bias = (EPI != 0) ? (Bias + (long)z * bZ) : nullptr;
  const int m0 = blockIdx.y * BM, n0 = blockIdx.x * BN;
  const int tid = threadIdx.x;
  const int tx = tid & 15, ty = tid >> 4;

  float acc[8][4];
#pragma unroll
  for (int i = 0; i < 8; ++i)
#pragma unroll
    for (int jn = 0; jn < 4; ++jn) acc[i][jn] = 0.f;

  for (int k0 = 0; k0 < K; k0 += BK) {
#pragma unroll
    for (int i = 0; i < 2; ++i) {
      int idx = tid + i * 256;
      int m = idx >> 2, k4 = (idx & 3) << 2;
      float4 v = *(const float4*)(A + (long)(m0 + m) * lda + k0 + k4);
      As[k4 + 0][m] = v.x; As[k4 + 1][m] = v.y;
      As[k4 + 2][m] = v.z; As[k4 + 3][m] = v.w;
    }
    {
      int k = tid >> 4, n4 = (tid & 15) << 2;
      float4 v = make_float4(0.f, 0.f, 0.f, 0.f);
      if (n0 + n4 < N) v = *(const float4*)(W + (long)(k0 + k) * ldw + n0 + n4);
      Bs[k][n4 + 0] = v.x; Bs[k][n4 + 1] = v.y;
      Bs[k][n4 + 2] = v.z; Bs[k][n4 + 3] = v.w;
    }
    __syncthreads();
#pragma unroll
    for (int kk = 0; kk < BK; ++kk) {
      float a[8], bb[4];
#pragma unroll
      for (int i = 0; i < 8; ++i) a[i] = As[kk][ty * 8 + i];
#pragma unroll
      for (int jn = 0; jn < 4; ++jn) bb[jn] = Bs[kk][tx * 4 + jn];
#pragma unroll
      for (int i = 0; i < 8; ++i)
#pragma unroll
        for (int jn = 0; jn < 4; ++jn) acc[i][jn] = fmaf(a[i], bb[jn], acc[i][jn]);
    }
    __syncthreads();
  }

  int n = n0 + tx * 4;
  if (n < N) {
#pragma unroll
    for (int i = 0; i < 8; ++i) {
      int m = m0 + ty * 8 + i;
      float4 v;
      float* vp = &v.x;
#pragma unroll
      for (int jn = 0; jn < 4; ++jn) {
        float val = acc[i][jn];
        if (EPI) val += bias[n + jn];
        if (EPI == 1) val = softplusf_(val);
        vp[jn] = val;
      }
      *(float4*)(C + (long)m * ldc + n) = v;
    }
  }
}

// ---------------- causal conv4 + silu --------------------------------------
__global__ __launch_bounds__(256) void conv_kernel(const float* __restrict__ UZ,
                                                   const float* __restrict__ Wconv,
                                                   const float* __restrict__ bconv,
                                                   float* __restrict__ uc, int stage) {
  long idx = (long)blockIdx.x * 256 + threadIdx.x;  // 8192*256
  int di = (int)(idx & 255);
  long r = idx >> 8;
  int l = (int)(r & 1023);
  int j = (int)(r >> 12);
  int lidx = stage + 2 * j;
  const float* wc = Wconv + (long)(lidx * 256 + di) * 4;
  float acc = bconv[lidx * 256 + di];
  const float* up = UZ + (r - 3) * 512 + di;
  if (l >= 3) {
    acc = fmaf(up[0], wc[0], acc);
    acc = fmaf(up[512], wc[1], acc);
    acc = fmaf(up[1024], wc[2], acc);
    acc = fmaf(up[1536], wc[3], acc);
  } else {
    for (int k = 3 - l; k < 4; ++k) acc = fmaf(up[(long)k * 512], wc[k], acc);
  }
  uc[idx] = acc * sigmoidf_(acc);
}

// ---------------- selective scan: chunked (CL=32), batched loads -----------
// Per thread: channel di, 32 states in registers. Loads of dt/uc/z are
// batched 8 columns at a time into double-buffered register arrays (all
// indices static after unroll) so one latency covers 8+ steps and the next
// batch's loads overlap this batch's ~2.5K-cycle compute (1 wave/SIMD grid).
template <int PASS>
__global__ __launch_bounds__(256)
void scan_chunk_kernel(const float* __restrict__ dt,
                       const float* __restrict__ uc,
                       const float* __restrict__ UZ,
                       const float* __restrict__ proj,
                       const float* __restrict__ Aneg,
                       const float* __restrict__ Dskip,
                       float* __restrict__ HST,   // [8][NC][256][32]
                       float* __restrict__ DTS,   // [8][NC][256]
                       unsigned short* __restrict__ YGh,
                       unsigned short* __restrict__ YGm,
                       unsigned short* __restrict__ YGl, int stage) {
  __shared__ __align__(16) float BC[SCAN_CL][64];
  const int blk = blockIdx.x;
  const int chunk = blk & (SCAN_NC - 1);
  const int jb = blk >> 5;
  const int di = threadIdx.x;
  const int j = jb >> 2;
  const int lidx = stage + 2 * j;
  const long r0 = (long)jb * 1024 + (long)chunk * SCAN_CL;

  for (int e = threadIdx.x; e < SCAN_CL * 64; e += 256) {
    int l = e >> 6, col = e & 63;
    BC[l][col] = proj[(r0 + l) * 80 + 16 + col];
  }

  float A[32];
  {
    const float4* ap = (const float4*)(Aneg + ((long)(lidx * 256 + di)) * 32);
#pragma unroll
    for (int q = 0; q < 8; ++q) {
      float4 v = ap[q];
      A[4 * q] = v.x; A[4 * q + 1] = v.y; A[4 * q + 2] = v.z; A[4 * q + 3] = v.w;
    }
  }

  const long sbase = (((long)jb * SCAN_NC + chunk) * 256 + di) * 32;
  float h[32];
  if (PASS == 0) {
#pragma unroll
    for (int n = 0; n < 32; ++n) h[n] = 0.f;
  } else {
    const float4* hp = (const float4*)(HST + sbase);
#pragma unroll
    for (int q = 0; q < 8; ++q) {
      float4 v = hp[q];
      h[4 * q] = v.x; h[4 * q + 1] = v.y; h[4 * q + 2] = v.z; h[4 * q + 3] = v.w;
    }
  }

  float Dsk = 0.f, dtsum = 0.f;
  if (PASS == 1) Dsk = Dskip[lidx * 256 + di];

  const float* dtp = dt + r0 * 256 + di;
  const float* up  = uc + r0 * 256 + di;
  const float* zp  = UZ + r0 * 512 + 256 + di;

  __syncthreads();

  float Db[2][8], Ub[2][8], Zb[2][8];
#pragma unroll
  for (int i = 0; i < 8; ++i) {
    Db[0][i] = dtp[(long)i * 256];
    Ub[0][i] = up[(long)i * 256];
    if (PASS == 1) Zb[0][i] = zp[(long)i * 512];
  }

#pragma unroll
  for (int bt = 0; bt < 4; ++bt) {
    const int cur = bt & 1, nxt = cur ^ 1;
    if (bt < 3) {
#pragma unroll
      for (int i = 0; i < 8; ++i) {
        long l = (long)(bt + 1) * 8 + i;
        Db[nxt][i] = dtp[l * 256];
        Ub[nxt][i] = up[l * 256];
        if (PASS == 1) Zb[nxt][i] = zp[l * 512];
      }
    }
#pragma unroll
    for (int i = 0; i < 8; ++i) {
      const int l = bt * 8 + i;
      float dtv = Db[cur][i];
      float uv  = Ub[cur][i];
      float du  = dtv * uv;
      if (PASS == 0) dtsum += dtv;
      float yacc[4] = {0.f, 0.f, 0.f, 0.f};
      const float4* bc4 = (const float4*)&BC[l][0];
#pragma unroll
      for (int q = 0; q < 8; ++q) {
        float4 bv = bc4[q];
        float4 cv = bc4[8 + q];
        const float* bp = &bv.x;
        const float* cp = &cv.x;
#pragma unroll
        for (int k = 0; k < 4; ++k) {
          int n = 4 * q + k;
          float a = EXP2(dtv * A[n]);     // A pre-scaled by log2(e)
          h[n] = fmaf(a, h[n], du * bp[k]);
          yacc[n & 3] = fmaf(h[n], cp[k], yacc[n & 3]);
        }
      }
      if (PASS == 1) {
        float y = (yacc[0] + yacc[1]) + (yacc[2] + yacc[3]);
        float zv = Zb[cur][i];
        float val = (y + uv * Dsk) * siluf_(zv);
        long o = swzi((r0 + l) * 256 + di, r0 + l);   // swizzled YG planes
        split3_(val, YGh[o], YGm[o], YGl[o]);
      }
    }
  }

  if (PASS == 0) {
    float4* hp = (float4*)(HST + sbase);
#pragma unroll
    for (int q = 0; q < 8; ++q)
      hp[q] = make_float4(h[4 * q], h[4 * q + 1], h[4 * q + 2], h[4 * q + 3]);
    DTS[((long)jb * SCAN_NC + chunk) * 256 + di] = dtsum;
  }
}

// ---------------- scan pass 2: sequential chunk combine --------------------
__global__ __launch_bounds__(256)
void scan_combine_kernel(float* __restrict__ HST, const float* __restrict__ DTS,
                         const float* __restrict__ Aneg, int stage) {
  int t = blockIdx.x * 256 + threadIdx.x;   // 65536
  int n = t & 31;
  int di = (t >> 5) & 255;
  int jb = t >> 13;
  int lidx = stage + 2 * (jb >> 2);
  float A = Aneg[((long)(lidx * 256 + di)) * 32 + n];   // pre-scaled by log2e
  float hs = 0.f;
  for (int c = 0; c < SCAN_NC; ++c) {
    long base = ((long)jb * SCAN_NC + c) * 256 + di;
    long idx = base * 32 + n;
    float s = HST[idx];
    HST[idx] = hs;
    float P = EXP2(A * DTS[base]);
    hs = fmaf(P, hs, s);
  }
}

// ---------------- final combine --------------------------------------------
__global__ __launch_bounds__(256) void combine_kernel(const float* __restrict__ H,
                                                      const float* __restrict__ gate,
                                                      const float* __restrict__ alpha,
                                                      const float* __restrict__ gamma,
                                                      const float* __restrict__ beta,
                                                      float* __restrict__ out) {
  long idx = (long)blockIdx.x * 256 + threadIdx.x;  // 1,048,576 (b,d,l)
  int l = (int)(idx & 1023);
  long t = idx >> 10;
  int d = (int)(t & 255);
  int b = (int)(t >> 8);
  int lr = 1023 - l;
  float h0 = H[(((long)b * 1024 + l) * 256) + d];
  float h1 = H[(((long)(4 + b) * 1024 + lr) * 256) + d];
  float g0 = gate[((long)(b * 256 + d)) * 1024 + l];
  float g1 = gate[(long)1024 * 1024 + ((long)(b * 256 + d)) * 1024 + lr];
  float m0 = (gamma[l] * tanhf(alpha[0] * h0) + beta[l]) * g0;
  float m1 = (gamma[1024 + lr] * tanhf(alpha[1] * h1) + beta[1024 + lr]) * g1;
  out[idx] = m0 + m1;
}

// ---------------------------------------------------------------------------
extern "C" void kernel_launch(void* const* d_in, const int* in_sizes, int n_in,
                              void* d_out, int out_size, void* d_ws, size_t ws_size,
                              hipStream_t stream) {
  const float* x     = (const float*)d_in[0];
  const float* Win   = (const float*)d_in[1];
  const float* Wconv = (const float*)d_in[2];
  const float* bconv = (const float*)d_in[3];
  const float* Wxp   = (const float*)d_in[4];
  const float* Wdt   = (const float*)d_in[5];
  const float* bdt   = (const float*)d_in[6];
  const float* Alog  = (const float*)d_in[7];
  const float* Dskip = (const float*)d_in[8];
  const float* Wout  = (const float*)d_in[9];
  const float* Wg    = (const float*)d_in[10];
  const float* bg    = (const float*)d_in[11];
  const float* alpha = (const float*)d_in[12];
  const float* gamma = (const float*)d_in[13];
  const float* beta  = (const float*)d_in[14];
  float* out = (float*)d_out;

  // ---- workspace layout (floats); total 20,873,216 f = 83.5 MB ----
  float* ws   = (float*)d_ws;
  float* UZ   = ws;                    // 4,194,304 f
  float* UC   = UZ + 4194304;          // 2,097,152 f
  float* PROJ = UC + 2097152;          // 655,360 f
  float* DT   = PROJ + 655360;         // 2,097,152 f
  float* GATE = DT + 2097152;          // 2,097,152 f
  float* ANEG = GATE + 2097152;        // 32,768 f
  float* HST  = ANEG + 32768;          // 2,097,152 f
  float* DTS  = HST + 2097152;         // 131,072 f
  unsigned short* Xpl  = (unsigned short*)(DTS + 131072);   // 3 x 2,097,152 u16
  unsigned short* YGpl = Xpl + 3 * 2097152;                 // 3 x 2,097,152 u16
  unsigned short* WinT = YGpl + 3 * 2097152;                // 3 x 524,288 u16
  unsigned short* WoutT = WinT + 3 * 524288;                // 3 x 262,144 u16
  // aliases
  float* PG  = UC;                          // 4 x 1,048,576 f partials
  float* XF  = UZ;                          // final H (stage-1 GEMM4 out)
  unsigned short* XGh = (unsigned short*)GATE;   // 3 x 1,048,576 u16
  unsigned short* XGm = XGh + 1048576;
  unsigned short* XGl = XGm + 1048576;
  unsigned short* Wgh = YGpl;                    // 3 x 2,097,152 u16
  unsigned short* Wgm = Wgh + 2097152;
  unsigned short* Wgl = Wgm + 2097152;
  unsigned short* Xh = Xpl, *Xm = Xpl + 2097152, *Xl = Xpl + 2 * 2097152;
  unsigned short* YGh = YGpl, *YGm = YGpl + 2097152, *YGl = YGpl + 2 * 2097152;
  unsigned short* WinTh = WinT, *WinTm = WinT + 524288, *WinTl = WinT + 2 * 524288;
  unsigned short* WoutTh = WoutT, *WoutTm = WoutT + 262144, *WoutTl = WoutT + 2 * 262144;

  // ---- prep / weight splitting (all planes written PRE-SWIZZLED) ----
  prep_kernel<<<dim3(8192), dim3(256), 0, stream>>>(x, Xh, Xm, Xl);
  aneg_kernel<<<dim3(128), dim3(256), 0, stream>>>(Alog, ANEG);
  split3v_kernel<<<dim3(1024), dim3(256), 0, stream>>>(
      (const float4*)x, XGh, XGm, XGl, 262144);
  split3v_kernel<<<dim3(2048), dim3(256), 0, stream>>>(
      (const float4*)Wg, Wgh, Wgm, Wgl, 524288);
  tconv3_kernel<<<dim3(16, 8, 4), dim3(256), 0, stream>>>(Win, WinTh, WinTm, WinTl, 256, 512);
  tconv3_kernel<<<dim3(8, 8, 4), dim3(256), 0, stream>>>(Wout, WoutTh, WoutTm, WoutTl, 256, 256);

  // ---- gate: PG[z*2+kh] = x @ Wg[z]^T (K-half kh); GATE = sigmoid(sum+bg) ----
  gemm_mfma<2><<<dim3(8, 8, 4), dim3(256), 0, stream>>>(
      XGh, XGm, XGl, 0L, 1024,
      Wgh, Wgm, Wgl, (long)1024 * 1024, 1024,
      PG, (long)1024 * 1024, 1024, 512);
  combine2_kernel<1><<<dim3(4096, 2), dim3(256), 0, stream>>>(
      PG, (long)1024 * 1024, bg, 1023, GATE, nullptr, nullptr, nullptr,
      (long)1024 * 1024);

  for (int s = 0; s < 2; ++s) {
    // GEMM1: UZ = X @ Win[lidx]  (N=512, K=256)
    gemm_mfma<1><<<dim3(4, 32, 2), dim3(256), 0, stream>>>(
        Xh, Xm, Xl, (long)4096 * 256, 256,
        WinTh + (long)s * 131072, WinTm + (long)s * 131072, WinTl + (long)s * 131072,
        (long)262144, 256,
        UZ, (long)4096 * 512, 512, 256);

    conv_kernel<<<dim3(8192), dim3(256), 0, stream>>>(UZ, Wconv, bconv, UC, s);

    // GEMM2: PROJ = UC @ Wxp[lidx] (N=80, fp32)
    gemm_f32<0><<<dim3(2, 32, 2), dim3(256), 0, stream>>>(
        UC, 256, (long)4096 * 256, Wxp + (long)s * 256 * 80, 80, (long)2 * 256 * 80,
        nullptr, 0, PROJ, 80, (long)4096 * 80, 4096, 80, 256);

    // GEMM3: DT = softplus(PROJ[:, :16] @ Wdt[lidx] + bdt[lidx])
    gemm_f32<1><<<dim3(4, 32, 2), dim3(256), 0, stream>>>(
        PROJ, 80, (long)4096 * 80, Wdt + (long)s * 16 * 256, 256, (long)2 * 16 * 256,
        bdt + s * 256, 512, DT, 256, (long)4096 * 256, 4096, 256, 16);

    // chunked selective scan (pass1 writes swizzled YG planes)
    scan_chunk_kernel<0><<<dim3(8 * SCAN_NC), dim3(256), 0, stream>>>(
        DT, UC, UZ, PROJ, ANEG, Dskip, HST, DTS, YGh, YGm, YGl, s);
    scan_combine_kernel<<<dim3(256), dim3(256), 0, stream>>>(HST, DTS, ANEG, s);
    scan_chunk_kernel<1><<<dim3(8 * SCAN_NC), dim3(256), 0, stream>>>(
        DT, UC, UZ, PROJ, ANEG, Dskip, HST, DTS, YGh, YGm, YGl, s);

    // GEMM4 (K-split): PG[z*2+kh] = YG @ Wout[lidx] (K-half), then combine
    gemm_mfma<2><<<dim3(2, 32, 4), dim3(256), 0, stream>>>(
        YGh, YGm, YGl, (long)4096 * 256, 256,
        WoutTh + (long)s * 65536, WoutTm + (long)s * 65536, WoutTl + (long)s * 65536,
        (long)131072, 256,
        PG, (long)4096 * 256, 256, 128);
    if (s == 0) {
      combine2_kernel<2><<<dim3(4096, 2), dim3(256), 0, stream>>>(
          PG, (long)4096 * 256, nullptr, 0, nullptr, Xh, Xm, Xl, (long)4096 * 256);
    } else {
      combine2_kernel<0><<<dim3(4096, 2), dim3(256), 0, stream>>>(
          PG, (long)4096 * 256, nullptr, 0, XF, nullptr, nullptr, nullptr,
          (long)4096 * 256);
    }
  }

  combine_kernel<<<dim3(4096), dim3(256), 0, stream>>>(XF, GATE, alpha, gamma, beta, out);
}

// Round 10
// 376.908 us; speedup vs baseline: 1.3401x; 1.0115x over previous
//
#include <hip/hip_runtime.h>

// ---------------------------------------------------------------------------
// MambaLatentBiMap: 2 branches (fwd / reversed) x 2 mamba layers + gates.
// Rows r = (j, b, l). Layer index for stage s, branch j: lidx = s + 2*j.
// MFMA GEMMs (gate, GEMM1, GEMM4): EXACT 3-way bf16 split (6 product terms ->
// fp32-equivalent), operands pre-split into 3 u16 planes by producers.
// gemm stages via global_load_lds (width 16); bank conflicts fixed by
// PRE-SWIZZLED global plane layout (swzi: k ^= ((row>>1)&3)<<3, involution).
// Scan: chunked linear recurrence. Round-10: CL=16/NC=64 (512 blocks = 2
// blocks/CU, doubles latency-hiding TLP; round-9's 1 wave/SIMD still stalled)
// + batched scan_combine (8-deep load batches, independent exp2 precompute).
// ---------------------------------------------------------------------------

#define LSEQ 1024
#define SCAN_CL 16
#define SCAN_NC 64

#if __has_builtin(__builtin_amdgcn_exp2f)
#define EXP2(x) __builtin_amdgcn_exp2f(x)
#else
#define EXP2(x) exp2f(x)
#endif

typedef short bf16x8 __attribute__((ext_vector_type(8)));
typedef float f32x4 __attribute__((ext_vector_type(4)));

__device__ __forceinline__ float sigmoidf_(float x) { return 1.f / (1.f + __expf(-x)); }
__device__ __forceinline__ float siluf_(float x)    { return x / (1.f + __expf(-x)); }
__device__ __forceinline__ float softplusf_(float x){ return x > 20.f ? x : log1pf(__expf(x)); }

__device__ __forceinline__ unsigned short bf16rne_(float v) {
  unsigned u = __float_as_uint(v);
  return (unsigned short)((u + 0x7FFFu + ((u >> 16) & 1u)) >> 16);
}
__device__ __forceinline__ float bfto_(unsigned short h) {
  return __uint_as_float(((unsigned)h) << 16);
}
__device__ __forceinline__ void split3_(float v, unsigned short& h,
                                        unsigned short& m, unsigned short& l) {
  h = bf16rne_(v); float r = v - bfto_(h);
  m = bf16rne_(r); float r2 = r - bfto_(m);
  l = bf16rne_(r2);
}

// swizzle: XOR k-bits 3-4 of a u16 plane index with row bits 1-2 (involution;
// valid since every plane K-dim is a multiple of 32).
__device__ __forceinline__ long swzi(long idx, long row) {
  return idx ^ (((row >> 1) & 3) << 3);
}

// ---------------- prep: x (B,D,L) -> X planes rows (j,b,l) cols d ----------
__global__ __launch_bounds__(256) void prep_kernel(const float* __restrict__ x,
                                                   unsigned short* __restrict__ Xh,
                                                   unsigned short* __restrict__ Xm,
                                                   unsigned short* __restrict__ Xl) {
  long idx = (long)blockIdx.x * 256 + threadIdx.x;   // 2,097,152
  int d = (int)(idx & 255);
  long t = idx >> 8;
  int l = (int)(t & 1023);
  int t2 = (int)(t >> 10);
  int b = t2 & 3;
  int j = t2 >> 2;
  int lsrc = j ? (1023 - l) : l;
  float v = x[((long)(b * 256 + d)) * LSEQ + lsrc];
  long o = swzi(idx, t);               // row = t, K = 256
  split3_(v, Xh[o], Xm[o], Xl[o]);
}

// ---------------- Aneg2 = -exp(Alog) * log2(e) -----------------------------
__global__ __launch_bounds__(256) void aneg_kernel(const float* __restrict__ Alog,
                                                   float* __restrict__ Aneg) {
  int idx = blockIdx.x * 256 + threadIdx.x;          // 32768
  Aneg[idx] = -__expf(Alog[idx]) * 1.4426950408889634f;
}

// ---------------- elementwise 3-way split, K=1024 planes (x gate, Wg) ------
__global__ __launch_bounds__(256) void split3v_kernel(const float4* __restrict__ in,
                                                      unsigned short* __restrict__ oh,
                                                      unsigned short* __restrict__ om,
                                                      unsigned short* __restrict__ ol, int n4) {
  int i = blockIdx.x * 256 + threadIdx.x;
  if (i >= n4) return;
  float4 v = in[i];
  long b = 4L * i;                     // u16 base index; row = b >> 10 (K=1024)
  long sb = swzi(b, b >> 10);          // float4 stays inside one 8-u16 chunk
  ushort4 H, M, L;
  split3_(v.x, H.x, M.x, L.x); split3_(v.y, H.y, M.y, L.y);
  split3_(v.z, H.z, M.z, L.z); split3_(v.w, H.w, M.w, L.w);
  *(ushort4*)(oh + sb) = H; *(ushort4*)(om + sb) = M; *(ushort4*)(ol + sb) = L;
}

// ---------------- transpose + 3-way split: [Z][K][N] -> [Z][N][K] ----------
__global__ __launch_bounds__(256) void tconv3_kernel(const float* __restrict__ in,
                                                     unsigned short* __restrict__ oh,
                                                     unsigned short* __restrict__ om,
                                                     unsigned short* __restrict__ ol,
                                                     int K, int N) {
  __shared__ float T[32][33];
  int z = blockIdx.z;
  int n0 = blockIdx.x * 32, k0 = blockIdx.y * 32;
  int tx = threadIdx.x & 31, ty = threadIdx.x >> 5;   // 32 x 8
  const float* src = in + (long)z * K * N;
#pragma unroll
  for (int m = 0; m < 4; ++m)
    T[ty + 8 * m][tx] = src[(long)(k0 + ty + 8 * m) * N + n0 + tx];
  __syncthreads();
  long obase = (long)z * N * K;
#pragma unroll
  for (int m = 0; m < 4; ++m) {
    float v = T[tx][ty + 8 * m];
    int n = n0 + ty + 8 * m;
    long o = swzi(obase + (long)n * K + k0 + tx, n);
    split3_(v, oh[o], om[o], ol[o]);
  }
}

// ---------------- MFMA 3-split bf16 GEMM (global_load_lds staging) ---------
__device__ __forceinline__ void gload16(const unsigned short* g, unsigned short* l) {
  __builtin_amdgcn_global_load_lds(
      (const __attribute__((address_space(1))) unsigned int*)g,
      (__attribute__((address_space(3))) unsigned int*)l, 16, 0, 0);
}

template <int KSPLIT>
__global__ __launch_bounds__(256)
void gemm_mfma(const unsigned short* __restrict__ Ah_g,
               const unsigned short* __restrict__ Am_g,
               const unsigned short* __restrict__ Al_g, long aZ, int lda,
               const unsigned short* __restrict__ Bh_g,
               const unsigned short* __restrict__ Bm_g,
               const unsigned short* __restrict__ Bl_g, long bZ, int ldb,
               float* __restrict__ C, long cZ, int N, int KH) {
  __shared__ unsigned short S[6][128 * 32];   // Ah Am Al Bh Bm Bl, 48 KB
  const int bz = blockIdx.z;
  const int z  = (KSPLIT == 2) ? (bz >> 1) : bz;
  const int kh = (KSPLIT == 2) ? (bz & 1) : 0;
  const int m0 = blockIdx.y * 128, n0 = blockIdx.x * 128;
  const int tid = threadIdx.x;

  const long khoff = (long)kh * KH;
  const long a0 = (long)z * aZ + (long)(m0 + (tid >> 2)) * lda + khoff + (tid & 3) * 8;
  const long a1 = a0 + 64L * lda;
  const long b0 = (long)z * bZ + (long)(n0 + (tid >> 2)) * ldb + khoff + (tid & 3) * 8;
  const long b1 = b0 + 64L * ldb;
  const int l0 = tid * 8, l1 = tid * 8 + 2048;   // u16 offsets into S[p]

  const int lane = tid & 63, w = tid >> 6;
  const int wr = w >> 1, wc = w & 1;
  const int fr = lane & 15, g = lane >> 4;

  f32x4 acc[4][4];
#pragma unroll
  for (int i = 0; i < 4; ++i)
#pragma unroll
    for (int j = 0; j < 4; ++j)
#pragma unroll
      for (int q = 0; q < 4; ++q) acc[i][j][q] = 0.f;

  for (int k0 = 0; k0 < KH; k0 += 32) {
    __syncthreads();   // protect LDS from readers of previous iteration
    gload16(Ah_g + a0 + k0, &S[0][l0]); gload16(Ah_g + a1 + k0, &S[0][l1]);
    gload16(Am_g + a0 + k0, &S[1][l0]); gload16(Am_g + a1 + k0, &S[1][l1]);
    gload16(Al_g + a0 + k0, &S[2][l0]); gload16(Al_g + a1 + k0, &S[2][l1]);
    gload16(Bh_g + b0 + k0, &S[3][l0]); gload16(Bh_g + b1 + k0, &S[3][l1]);
    gload16(Bm_g + b0 + k0, &S[4][l0]); gload16(Bm_g + b1 + k0, &S[4][l1]);
    gload16(Bl_g + b0 + k0, &S[5][l0]); gload16(Bl_g + b1 + k0, &S[5][l1]);
    __syncthreads();   // drains vmcnt -> staged data visible

    bf16x8 fb[3][4];
#pragma unroll
    for (int nf = 0; nf < 4; ++nf) {
      int rb = wc * 64 + nf * 16 + fr;
      int ob = rb * 32 + ((g ^ ((rb >> 1) & 3)) << 3);
      fb[0][nf] = *(const bf16x8*)&S[3][ob];
      fb[1][nf] = *(const bf16x8*)&S[4][ob];
      fb[2][nf] = *(const bf16x8*)&S[5][ob];
    }
#pragma unroll
    for (int mf = 0; mf < 4; ++mf) {
      int ra = wr * 64 + mf * 16 + fr;
      int oa = ra * 32 + ((g ^ ((ra >> 1) & 3)) << 3);
      bf16x8 fah = *(const bf16x8*)&S[0][oa];
      bf16x8 fam = *(const bf16x8*)&S[1][oa];
      bf16x8 fal = *(const bf16x8*)&S[2][oa];
#pragma unroll
      for (int nf = 0; nf < 4; ++nf) {
        acc[mf][nf] = __builtin_amdgcn_mfma_f32_16x16x32_bf16(fah, fb[0][nf], acc[mf][nf], 0, 0, 0);
        acc[mf][nf] = __builtin_amdgcn_mfma_f32_16x16x32_bf16(fah, fb[1][nf], acc[mf][nf], 0, 0, 0);
        acc[mf][nf] = __builtin_amdgcn_mfma_f32_16x16x32_bf16(fam, fb[0][nf], acc[mf][nf], 0, 0, 0);
        acc[mf][nf] = __builtin_amdgcn_mfma_f32_16x16x32_bf16(fam, fb[1][nf], acc[mf][nf], 0, 0, 0);
        acc[mf][nf] = __builtin_amdgcn_mfma_f32_16x16x32_bf16(fah, fb[2][nf], acc[mf][nf], 0, 0, 0);
        acc[mf][nf] = __builtin_amdgcn_mfma_f32_16x16x32_bf16(fal, fb[0][nf], acc[mf][nf], 0, 0, 0);
      }
    }
  }

  float* Cz = C + (long)bz * cZ;
#pragma unroll
  for (int mf = 0; mf < 4; ++mf)
#pragma unroll
    for (int nf = 0; nf < 4; ++nf) {
      int col = n0 + wc * 64 + nf * 16 + fr;
      int row0 = m0 + wr * 64 + mf * 16 + g * 4;
#pragma unroll
      for (int q = 0; q < 4; ++q)
        Cz[(long)(row0 + q) * N + col] = acc[mf][nf][q];
    }
}

// ---------------- combine2: sum two K-split partial planes + epilogue ------
// OP: 0 plain f32, 1 sigmoid(v + bias), 2 split3 -> swizzled planes (K=256)
template <int OP>
__global__ __launch_bounds__(256)
void combine2_kernel(const float* __restrict__ P, long pz,
                     const float* __restrict__ bias, int nmask,
                     float* __restrict__ outF,
                     unsigned short* __restrict__ oh,
                     unsigned short* __restrict__ om,
                     unsigned short* __restrict__ ol, long oz) {
  int z = blockIdx.y;
  long i = (long)blockIdx.x * 256 + threadIdx.x;
  float v = P[(long)(2 * z) * pz + i] + P[(long)(2 * z + 1) * pz + i];
  if (OP == 1) {
    outF[(long)z * oz + i] = sigmoidf_(v + bias[z * (nmask + 1) + (int)(i & nmask)]);
  } else if (OP == 0) {
    outF[(long)z * oz + i] = v;
  } else {
    long o = (long)z * oz + swzi(i, i >> 8);   // row = i>>8, K = 256
    split3_(v, oh[o], om[o], ol[o]);
  }
}

// ---------------- generic tiled fp32 GEMM (GEMM2, GEMM3) -------------------
template <int EPI>   // 0 none, 1 bias+softplus
__global__ __launch_bounds__(256)
void gemm_f32(const float* __restrict__ A, int lda, long aZ,
              const float* __restrict__ W, int ldw, long wZ,
              const float* __restrict__ Bias, long bZ,
              float* __restrict__ C, int ldc, long cZ,
              int M, int N, int K) {
  constexpr int BM = 128, BN = 64, BK = 16;
  __shared__ __align__(16) float As[BK][BM];
  __shared__ __align__(16) float Bs[BK][BN];
  const int z = blockIdx.z;
  A += (long)z * aZ;
  W += (long)z * wZ;
  C += (long)z * cZ;
  const float* bias = (EPI != 0) ? (Bias + (long)z * bZ) : nullptr;
  const int m0 = blockIdx.y * BM, n0 = blockIdx.x * BN;
  const int tid = threadIdx.x;
  const int tx = tid & 15, ty = tid >> 4;

  float acc[8][4];
#pragma unroll
  for (int i = 0; i < 8; ++i)
#pragma unroll
    for (int jn = 0; jn < 4; ++jn) acc[i][jn] = 0.f;

  for (int k0 = 0; k0 < K; k0 += BK) {
#pragma unroll
    for (int i = 0; i < 2; ++i) {
      int idx = tid + i * 256;
      int m = idx >> 2, k4 = (idx & 3) << 2;
      float4 v = *(const float4*)(A + (long)(m0 + m) * lda + k0 + k4);
      As[k4 + 0][m] = v.x; As[k4 + 1][m] = v.y;
      As[k4 + 2][m] = v.z; As[k4 + 3][m] = v.w;
    }
    {
      int k = tid >> 4, n4 = (tid & 15) << 2;
      float4 v = make_float4(0.f, 0.f, 0.f, 0.f);
      if (n0 + n4 < N) v = *(const float4*)(W + (long)(k0 + k) * ldw + n0 + n4);
      Bs[k][n4 + 0] = v.x; Bs[k][n4 + 1] = v.y;
      Bs[k][n4 + 2] = v.z; Bs[k][n4 + 3] = v.w;
    }
    __syncthreads();
#pragma unroll
    for (int kk = 0; kk < BK; ++kk) {
      float a[8], bb[4];
#pragma unroll
      for (int i = 0; i < 8; ++i) a[i] = As[kk][ty * 8 + i];
#pragma unroll
      for (int jn = 0; jn < 4; ++jn) bb[jn] = Bs[kk][tx * 4 + jn];
#pragma unroll
      for (int i = 0; i < 8; ++i)
#pragma unroll
        for (int jn = 0; jn < 4; ++jn) acc[i][jn] = fmaf(a[i], bb[jn], acc[i][jn]);
    }
    __syncthreads();
  }

  int n = n0 + tx * 4;
  if (n < N) {
#pragma unroll
    for (int i = 0; i < 8; ++i) {
      int m = m0 + ty * 8 + i;
      float4 v;
      float* vp = &v.x;
#pragma unroll
      for (int jn = 0; jn < 4; ++jn) {
        float val = acc[i][jn];
        if (EPI) val += bias[n + jn];
        if (EPI == 1) val = softplusf_(val);
        vp[jn] = val;
      }
      *(float4*)(C + (long)m * ldc + n) = v;
    }
  }
}

// ---------------- causal conv4 + silu --------------------------------------
__global__ __launch_bounds__(256) void conv_kernel(const float* __restrict__ UZ,
                                                   const float* __restrict__ Wconv,
                                                   const float* __restrict__ bconv,
                                                   float* __restrict__ uc, int stage) {
  long idx = (long)blockIdx.x * 256 + threadIdx.x;  // 8192*256
  int di = (int)(idx & 255);
  long r = idx >> 8;
  int l = (int)(r & 1023);
  int j = (int)(r >> 12);
  int lidx = stage + 2 * j;
  const float* wc = Wconv + (long)(lidx * 256 + di) * 4;
  float acc = bconv[lidx * 256 + di];
  const float* up = UZ + (r - 3) * 512 + di;
  if (l >= 3) {
    acc = fmaf(up[0], wc[0], acc);
    acc = fmaf(up[512], wc[1], acc);
    acc = fmaf(up[1024], wc[2], acc);
    acc = fmaf(up[1536], wc[3], acc);
  } else {
    for (int k = 3 - l; k < 4; ++k) acc = fmaf(up[(long)k * 512], wc[k], acc);
  }
  uc[idx] = acc * sigmoidf_(acc);
}

// ---------------- selective scan: chunked (CL=16), batched loads -----------
// Per thread: channel di, 32 states in registers. 512 blocks (2 blocks/CU =
// 2 waves/SIMD) + 8-column double-buffered register load batches.
template <int PASS>
__global__ __launch_bounds__(256)
void scan_chunk_kernel(const float* __restrict__ dt,
                       const float* __restrict__ uc,
                       const float* __restrict__ UZ,
                       const float* __restrict__ proj,
                       const float* __restrict__ Aneg,
                       const float* __restrict__ Dskip,
                       float* __restrict__ HST,   // [8][NC][256][32]
                       float* __restrict__ DTS,   // [8][NC][256]
                       unsigned short* __restrict__ YGh,
                       unsigned short* __restrict__ YGm,
                       unsigned short* __restrict__ YGl, int stage) {
  __shared__ __align__(16) float BC[SCAN_CL][64];
  const int blk = blockIdx.x;
  const int chunk = blk & (SCAN_NC - 1);
  const int jb = blk >> 6;
  const int di = threadIdx.x;
  const int j = jb >> 2;
  const int lidx = stage + 2 * j;
  const long r0 = (long)jb * 1024 + (long)chunk * SCAN_CL;

  for (int e = threadIdx.x; e < SCAN_CL * 64; e += 256) {
    int l = e >> 6, col = e & 63;
    BC[l][col] = proj[(r0 + l) * 80 + 16 + col];
  }

  float A[32];
  {
    const float4* ap = (const float4*)(Aneg + ((long)(lidx * 256 + di)) * 32);
#pragma unroll
    for (int q = 0; q < 8; ++q) {
      float4 v = ap[q];
      A[4 * q] = v.x; A[4 * q + 1] = v.y; A[4 * q + 2] = v.z; A[4 * q + 3] = v.w;
    }
  }

  const long sbase = (((long)jb * SCAN_NC + chunk) * 256 + di) * 32;
  float h[32];
  if (PASS == 0) {
#pragma unroll
    for (int n = 0; n < 32; ++n) h[n] = 0.f;
  } else {
    const float4* hp = (const float4*)(HST + sbase);
#pragma unroll
    for (int q = 0; q < 8; ++q) {
      float4 v = hp[q];
      h[4 * q] = v.x; h[4 * q + 1] = v.y; h[4 * q + 2] = v.z; h[4 * q + 3] = v.w;
    }
  }

  float Dsk = 0.f, dtsum = 0.f;
  if (PASS == 1) Dsk = Dskip[lidx * 256 + di];

  const float* dtp = dt + r0 * 256 + di;
  const float* up  = uc + r0 * 256 + di;
  const float* zp  = UZ + r0 * 512 + 256 + di;

  __syncthreads();

  float Db[2][8], Ub[2][8], Zb[2][8];
#pragma unroll
  for (int i = 0; i < 8; ++i) {
    Db[0][i] = dtp[(long)i * 256];
    Ub[0][i] = up[(long)i * 256];
    if (PASS == 1) Zb[0][i] = zp[(long)i * 512];
  }

#pragma unroll
  for (int bt = 0; bt < SCAN_CL / 8; ++bt) {
    const int cur = bt & 1, nxt = cur ^ 1;
    if (bt < SCAN_CL / 8 - 1) {
#pragma unroll
      for (int i = 0; i < 8; ++i) {
        long l = (long)(bt + 1) * 8 + i;
        Db[nxt][i] = dtp[l * 256];
        Ub[nxt][i] = up[l * 256];
        if (PASS == 1) Zb[nxt][i] = zp[l * 512];
      }
    }
#pragma unroll
    for (int i = 0; i < 8; ++i) {
      const int l = bt * 8 + i;
      float dtv = Db[cur][i];
      float uv  = Ub[cur][i];
      float du  = dtv * uv;
      if (PASS == 0) dtsum += dtv;
      float yacc[4] = {0.f, 0.f, 0.f, 0.f};
      const float4* bc4 = (const float4*)&BC[l][0];
#pragma unroll
      for (int q = 0; q < 8; ++q) {
        float4 bv = bc4[q];
        float4 cv = bc4[8 + q];
        const float* bp = &bv.x;
        const float* cp = &cv.x;
#pragma unroll
        for (int k = 0; k < 4; ++k) {
          int n = 4 * q + k;
          float a = EXP2(dtv * A[n]);     // A pre-scaled by log2(e)
          h[n] = fmaf(a, h[n], du * bp[k]);
          yacc[n & 3] = fmaf(h[n], cp[k], yacc[n & 3]);
        }
      }
      if (PASS == 1) {
        float y = (yacc[0] + yacc[1]) + (yacc[2] + yacc[3]);
        float zv = Zb[cur][i];
        float val = (y + uv * Dsk) * siluf_(zv);
        long o = swzi((r0 + l) * 256 + di, r0 + l);   // swizzled YG planes
        split3_(val, YGh[o], YGm[o], YGl[o]);
      }
    }
  }

  if (PASS == 0) {
    float4* hp = (float4*)(HST + sbase);
#pragma unroll
    for (int q = 0; q < 8; ++q)
      hp[q] = make_float4(h[4 * q], h[4 * q + 1], h[4 * q + 2], h[4 * q + 3]);
    DTS[((long)jb * SCAN_NC + chunk) * 256 + di] = dtsum;
  }
}

// ---------------- scan pass 2: sequential chunk combine (batched) ----------
// hs chain is 8 fma per batch; loads and exp2 of each 8-chunk batch are
// independent and issued together (breaks the per-chunk latency chain).
__global__ __launch_bounds__(256)
void scan_combine_kernel(float* __restrict__ HST, const float* __restrict__ DTS,
                         const float* __restrict__ Aneg, int stage) {
  int t = blockIdx.x * 256 + threadIdx.x;   // 65536
  int n = t & 31;
  int di = (t >> 5) & 255;
  int jb = t >> 13;
  int lidx = stage + 2 * (jb >> 2);
  float A = Aneg[((long)(lidx * 256 + di)) * 32 + n];   // pre-scaled by log2e
  float hs = 0.f;
  for (int cb = 0; cb < SCAN_NC; cb += 8) {
    float s[8], P[8], hv[8];
#pragma unroll
    for (int i = 0; i < 8; ++i) {
      long base = ((long)jb * SCAN_NC + cb + i) * 256 + di;
      s[i] = HST[base * 32 + n];
      P[i] = DTS[base];
    }
#pragma unroll
    for (int i = 0; i < 8; ++i) P[i] = EXP2(A * P[i]);
#pragma unroll
    for (int i = 0; i < 8; ++i) {
      hv[i] = hs;
      hs = fmaf(P[i], hs, s[i]);
    }
#pragma unroll
    for (int i = 0; i < 8; ++i) {
      long base = ((long)jb * SCAN_NC + cb + i) * 256 + di;
      HST[base * 32 + n] = hv[i];
    }
  }
}

// ---------------- final combine --------------------------------------------
__global__ __launch_bounds__(256) void combine_kernel(const float* __restrict__ H,
                                                      const float* __restrict__ gate,
                                                      const float* __restrict__ alpha,
                                                      const float* __restrict__ gamma,
                                                      const float* __restrict__ beta,
                                                      float* __restrict__ out) {
  long idx = (long)blockIdx.x * 256 + threadIdx.x;  // 1,048,576 (b,d,l)
  int l = (int)(idx & 1023);
  long t = idx >> 10;
  int d = (int)(t & 255);
  int b = (int)(t >> 8);
  int lr = 1023 - l;
  float h0 = H[(((long)b * 1024 + l) * 256) + d];
  float h1 = H[(((long)(4 + b) * 1024 + lr) * 256) + d];
  float g0 = gate[((long)(b * 256 + d)) * 1024 + l];
  float g1 = gate[(long)1024 * 1024 + ((long)(b * 256 + d)) * 1024 + lr];
  float m0 = (gamma[l] * tanhf(alpha[0] * h0) + beta[l]) * g0;
  float m1 = (gamma[1024 + lr] * tanhf(alpha[1] * h1) + beta[1024 + lr]) * g1;
  out[idx] = m0 + m1;
}

// ---------------------------------------------------------------------------
extern "C" void kernel_launch(void* const* d_in, const int* in_sizes, int n_in,
                              void* d_out, int out_size, void* d_ws, size_t ws_size,
                              hipStream_t stream) {
  const float* x     = (const float*)d_in[0];
  const float* Win   = (const float*)d_in[1];
  const float* Wconv = (const float*)d_in[2];
  const float* bconv = (const float*)d_in[3];
  const float* Wxp   = (const float*)d_in[4];
  const float* Wdt   = (const float*)d_in[5];
  const float* bdt   = (const float*)d_in[6];
  const float* Alog  = (const float*)d_in[7];
  const float* Dskip = (const float*)d_in[8];
  const float* Wout  = (const float*)d_in[9];
  const float* Wg    = (const float*)d_in[10];
  const float* bg    = (const float*)d_in[11];
  const float* alpha = (const float*)d_in[12];
  const float* gamma = (const float*)d_in[13];
  const float* beta  = (const float*)d_in[14];
  float* out = (float*)d_out;

  // ---- workspace layout (floats); ws_size = 256 MB (round-9 fill counters),
  // total used 91.5 MB ----
  float* ws   = (float*)d_ws;
  float* UZ   = ws;                    // 4,194,304 f
  float* UC   = UZ + 4194304;          // 2,097,152 f
  float* PROJ = UC + 2097152;          // 655,360 f
  float* DT   = PROJ + 655360;         // 2,097,152 f
  float* GATE = DT + 2097152;          // 2,097,152 f
  float* ANEG = GATE + 2097152;        // 32,768 f
  float* HST  = ANEG + 32768;          // 4,194,304 f  (NC=64)
  float* DTS  = HST + 4194304;         // 131,072 f
  unsigned short* Xpl  = (unsigned short*)(DTS + 131072);   // 3 x 2,097,152 u16
  unsigned short* YGpl = Xpl + 3 * 2097152;                 // 3 x 2,097,152 u16
  unsigned short* WinT = YGpl + 3 * 2097152;                // 3 x 524,288 u16
  unsigned short* WoutT = WinT + 3 * 524288;                // 3 x 262,144 u16
  // aliases
  float* PG  = UC;                          // 4 x 1,048,576 f partials
  float* XF  = UZ;                          // final H (stage-1 GEMM4 out)
  unsigned short* XGh = (unsigned short*)GATE;   // 3 x 1,048,576 u16
  unsigned short* XGm = XGh + 1048576;
  unsigned short* XGl = XGm + 1048576;
  unsigned short* Wgh = YGpl;                    // 3 x 2,097,152 u16
  unsigned short* Wgm = Wgh + 2097152;
  unsigned short* Wgl = Wgm + 2097152;
  unsigned short* Xh = Xpl, *Xm = Xpl + 2097152, *Xl = Xpl + 2 * 2097152;
  unsigned short* YGh = YGpl, *YGm = YGpl + 2097152, *YGl = YGpl + 2 * 2097152;
  unsigned short* WinTh = WinT, *WinTm = WinT + 524288, *WinTl = WinT + 2 * 524288;
  unsigned short* WoutTh = WoutT, *WoutTm = WoutT + 262144, *WoutTl = WoutT + 2 * 262144;

  // ---- prep / weight splitting (all planes written PRE-SWIZZLED) ----
  prep_kernel<<<dim3(8192), dim3(256), 0, stream>>>(x, Xh, Xm, Xl);
  aneg_kernel<<<dim3(128), dim3(256), 0, stream>>>(Alog, ANEG);
  split3v_kernel<<<dim3(1024), dim3(256), 0, stream>>>(
      (const float4*)x, XGh, XGm, XGl, 262144);
  split3v_kernel<<<dim3(2048), dim3(256), 0, stream>>>(
      (const float4*)Wg, Wgh, Wgm, Wgl, 524288);
  tconv3_kernel<<<dim3(16, 8, 4), dim3(256), 0, stream>>>(Win, WinTh, WinTm, WinTl, 256, 512);
  tconv3_kernel<<<dim3(8, 8, 4), dim3(256), 0, stream>>>(Wout, WoutTh, WoutTm, WoutTl, 256, 256);

  // ---- gate: PG[z*2+kh] = x @ Wg[z]^T (K-half kh); GATE = sigmoid(sum+bg) ----
  gemm_mfma<2><<<dim3(8, 8, 4), dim3(256), 0, stream>>>(
      XGh, XGm, XGl, 0L, 1024,
      Wgh, Wgm, Wgl, (long)1024 * 1024, 1024,
      PG, (long)1024 * 1024, 1024, 512);
  combine2_kernel<1><<<dim3(4096, 2), dim3(256), 0, stream>>>(
      PG, (long)1024 * 1024, bg, 1023, GATE, nullptr, nullptr, nullptr,
      (long)1024 * 1024);

  for (int s = 0; s < 2; ++s) {
    // GEMM1: UZ = X @ Win[lidx]  (N=512, K=256)
    gemm_mfma<1><<<dim3(4, 32, 2), dim3(256), 0, stream>>>(
        Xh, Xm, Xl, (long)4096 * 256, 256,
        WinTh + (long)s * 131072, WinTm + (long)s * 131072, WinTl + (long)s * 131072,
        (long)262144, 256,
        UZ, (long)4096 * 512, 512, 256);

    conv_kernel<<<dim3(8192), dim3(256), 0, stream>>>(UZ, Wconv, bconv, UC, s);

    // GEMM2: PROJ = UC @ Wxp[lidx] (N=80, fp32)
    gemm_f32<0><<<dim3(2, 32, 2), dim3(256), 0, stream>>>(
        UC, 256, (long)4096 * 256, Wxp + (long)s * 256 * 80, 80, (long)2 * 256 * 80,
        nullptr, 0, PROJ, 80, (long)4096 * 80, 4096, 80, 256);

    // GEMM3: DT = softplus(PROJ[:, :16] @ Wdt[lidx] + bdt[lidx])
    gemm_f32<1><<<dim3(4, 32, 2), dim3(256), 0, stream>>>(
        PROJ, 80, (long)4096 * 80, Wdt + (long)s * 16 * 256, 256, (long)2 * 16 * 256,
        bdt + s * 256, 512, DT, 256, (long)4096 * 256, 4096, 256, 16);

    // chunked selective scan (pass1 writes swizzled YG planes)
    scan_chunk_kernel<0><<<dim3(8 * SCAN_NC), dim3(256), 0, stream>>>(
        DT, UC, UZ, PROJ, ANEG, Dskip, HST, DTS, YGh, YGm, YGl, s);
    scan_combine_kernel<<<dim3(256), dim3(256), 0, stream>>>(HST, DTS, ANEG, s);
    scan_chunk_kernel<1><<<dim3(8 * SCAN_NC), dim3(256), 0, stream>>>(
        DT, UC, UZ, PROJ, ANEG, Dskip, HST, DTS, YGh, YGm, YGl, s);

    // GEMM4 (K-split): PG[z*2+kh] = YG @ Wout[lidx] (K-half), then combine
    gemm_mfma<2><<<dim3(2, 32, 4), dim3(256), 0, stream>>>(
        YGh, YGm, YGl, (long)4096 * 256, 256,
        WoutTh + (long)s * 65536, WoutTm + (long)s * 65536, WoutTl + (long)s * 65536,
        (long)131072, 256,
        PG, (long)4096 * 256, 256, 128);
    if (s == 0) {
      combine2_kernel<2><<<dim3(4096, 2), dim3(256), 0, stream>>>(
          PG, (long)4096 * 256, nullptr, 0, nullptr, Xh, Xm, Xl, (long)4096 * 256);
    } else {
      combine2_kernel<0><<<dim3(4096, 2), dim3(256), 0, stream>>>(
          PG, (long)4096 * 256, nullptr, 0, XF, nullptr, nullptr, nullptr,
          (long)4096 * 256);
    }
  }

  combine_kernel<<<dim3(4096), dim3(256), 0, stream>>>(XF, GATE, alpha, gamma, beta, out);
}